// Round 4
// baseline (656.554 us; speedup 1.0000x reference)
//
#include <hip/hip_runtime.h>
#include <hip/hip_fp16.h>
#include <cstdint>
#include <cstddef>

#define N_NODES   262144
#define NG        256
#define PP        1024
#define NE        4194304
#define FIN       128
#define HH        32
#define NC        10
#define OL        16
#define IL        96
#define NITER     3
#define ECHUNK    4096
#define NCHUNK    (NE/ECHUNK)   // 1024
#define ECAP      18432
#define HSTR      36            // 32 data cols + 4 pad cols (pads hold W1 during GEMM1)
#define PLSTR     20            // priors LDS stride (floats): 16B-aligned, 8 bank-groups

typedef _Float16 half8 __attribute__((ext_vector_type(8)));
typedef float f32x4 __attribute__((ext_vector_type(4)));

__device__ __forceinline__ float tanh_fast(float x) {
  float e = __expf(2.0f * x);
  return 1.0f - 2.0f / (e + 1.0f);
}
__device__ __forceinline__ unsigned pk2(float a, float b) {
  __half2 h = __floats2half2_rn(a, b);
  return *reinterpret_cast<unsigned*>(&h);
}

// ---------------- per-chunk per-graph edge histogram (transposed output) ----------------
__global__ void k_hist(const int* __restrict__ ei, unsigned* __restrict__ histT) {
  __shared__ unsigned lh[NG];
  int t = threadIdx.x, b = blockIdx.x;
  lh[t] = 0;
  __syncthreads();
  int base = b * ECHUNK;
  for (int q = t; q < ECHUNK; q += 256) {
    int e = base + q;
    int s = ei[e], d = ei[NE + e];
    if (s != d) atomicAdd(&lh[s >> 10], 1u);
  }
  __syncthreads();
  histT[t * NCHUNK + b] = lh[t];   // [g][ch]
}

// ---------------- per-graph scan over chunks: cbaseT[ch][g] (within-graph excl), gtot[g] ---
__global__ void k_scanA(const unsigned* __restrict__ histT, unsigned* __restrict__ cbaseT,
                        unsigned* __restrict__ gtot) {
  __shared__ unsigned wtot[4];
  int t = threadIdx.x, g = blockIdx.x;
  int lane = t & 63, wv = t >> 6;
  uint4 hv = *(const uint4*)(histT + (size_t)g * NCHUNK + t * 4);
  unsigned s0 = hv.x, s1 = s0 + hv.y, s2 = s1 + hv.z, s3 = s2 + hv.w;
  unsigned tsum = s3, sc = tsum;
  for (int d = 1; d < 64; d <<= 1) {
    unsigned v = __shfl_up(sc, d, 64);
    if (lane >= d) sc += v;
  }
  if (lane == 63) wtot[wv] = sc;
  __syncthreads();
  unsigned woff = 0;
  for (int w = 0; w < wv; ++w) woff += wtot[w];
  unsigned base = woff + sc - tsum;   // exclusive
  cbaseT[(size_t)(t * 4 + 0) * NG + g] = base;
  cbaseT[(size_t)(t * 4 + 1) * NG + g] = base + s0;
  cbaseT[(size_t)(t * 4 + 2) * NG + g] = base + s1;
  cbaseT[(size_t)(t * 4 + 3) * NG + g] = base + s2;
  if (t == 255) gtot[g] = woff + sc;
}

// ---------------- scan of per-graph totals -> gbase[257] ----------------
__global__ void k_scanB(const unsigned* __restrict__ gtot, unsigned* __restrict__ gbase) {
  __shared__ unsigned wtot[4];
  int t = threadIdx.x;
  int lane = t & 63, wv = t >> 6;
  unsigned x = gtot[t], sc = x;
  for (int d = 1; d < 64; d <<= 1) {
    unsigned v = __shfl_up(sc, d, 64);
    if (lane >= d) sc += v;
  }
  if (lane == 63) wtot[wv] = sc;
  __syncthreads();
  unsigned woff = 0;
  for (int w = 0; w < wv; ++w) woff += wtot[w];
  gbase[t] = woff + sc - x;
  if (t == 255) gbase[256] = woff + sc;
}

// ---------------- scatter edges into graph buckets ----------------
__global__ void k_scatter(const int* __restrict__ ei, const unsigned* __restrict__ cbaseT,
                          const unsigned* __restrict__ gbase, unsigned* __restrict__ epack) {
  __shared__ unsigned lcur[NG];
  int t = threadIdx.x, b = blockIdx.x;
  lcur[t] = gbase[t] + cbaseT[(size_t)b * NG + t];
  __syncthreads();
  int base = b * ECHUNK;
  for (int q = t; q < ECHUNK; q += 256) {
    int e = base + q;
    int s = ei[e], d = ei[NE + e];
    if (s != d) {
      int g = s >> 10;
      unsigned pos = atomicAdd(&lcur[g], 1u);
      epack[pos] = (unsigned)(s & 1023) | ((unsigned)(d & 1023) << 10);
    }
  }
}

// ---------------- per-graph counting sort by dst offset -> CSR + u16 src list ------------
__global__ __launch_bounds__(256) void k_dstsort(const unsigned* __restrict__ epack,
                          const unsigned* __restrict__ gbase,
                          unsigned short* __restrict__ esrc16,
                          unsigned* __restrict__ dstptr) {
  __shared__ unsigned shist[PP];
  __shared__ unsigned wsum[256];
  __shared__ unsigned cur[PP];
  int t = threadIdx.x, g = blockIdx.x;
  unsigned e0 = gbase[g], e1 = gbase[g + 1];
  for (int i = t; i < PP; i += 256) shist[i] = 0;
  __syncthreads();
  for (unsigned e = e0 + t; e < e1; e += 256)
    atomicAdd(&shist[(epack[e] >> 10) & 1023], 1u);
  __syncthreads();
  unsigned h0 = shist[4 * t], h1 = shist[4 * t + 1], h2 = shist[4 * t + 2], h3 = shist[4 * t + 3];
  unsigned tsum = h0 + h1 + h2 + h3;
  wsum[t] = tsum;
  __syncthreads();
  for (int off = 1; off < 256; off <<= 1) {
    unsigned v = (t >= off) ? wsum[t - off] : 0u;
    __syncthreads();
    wsum[t] += v;
    __syncthreads();
  }
  unsigned excl = wsum[t] - tsum;
  unsigned c0 = excl, c1 = c0 + h0, c2 = c1 + h1, c3 = c2 + h2;
  cur[4 * t] = c0; cur[4 * t + 1] = c1; cur[4 * t + 2] = c2; cur[4 * t + 3] = c3;
  unsigned* dp = dstptr + (size_t)g * (PP + 1);
  dp[4 * t] = c0; dp[4 * t + 1] = c1; dp[4 * t + 2] = c2; dp[4 * t + 3] = c3;
  if (t == 0) dp[PP] = e1 - e0;
  __syncthreads();
  unsigned short* eg = esrc16 + (size_t)g * ECAP;
  for (unsigned e = e0 + t; e < e1; e += 256) {
    unsigned pk = epack[e];
    unsigned so = pk & 1023, dofs = (pk >> 10) & 1023;
    unsigned pos = atomicAdd(&cur[dofs], 1u);
    if (pos < ECAP) eg[pos] = (unsigned short)so;
  }
}

// ---------------- dis from CSR degrees ----------------
__global__ void k_dis(const unsigned* __restrict__ dstptr, float* __restrict__ dis) {
  int n = blockIdx.x * 256 + threadIdx.x;
  int g = n >> 10, k = n & 1023;
  const unsigned* dp = dstptr + (size_t)g * (PP + 1) + k;
  float deg = (float)(dp[1] - dp[0]);
  dis[n] = 1.0f / sqrtf(deg + 1.0f);
}

// ---------------- one GCN layer: gather from hsl -> tanh -> h16 cols; optional in-thread
// 32x32 linear with W from GLOBAL (scalar loads) -> overwrite hsl with hlin_next * d -------
__device__ __forceinline__ void gcn_layer(float* hsl, const float* dg, const unsigned* dp,
                                          const unsigned short* eg, const float* bias,
                                          int coloff, const float* Wn, __half* hb16,
                                          float* keyArr, int t) {
  float4 bl[8];
#pragma unroll
  for (int j = 0; j < 8; ++j) bl[j] = ((const float4*)bias)[j];
  float xn[2][32];
#pragma unroll
  for (int pth = 0; pth < 2; ++pth) {
    int k = t + pth * 512;
    float dk = dg[k];
    unsigned e0 = dp[k], e1 = dp[k + 1];
    if (e1 > (unsigned)ECAP) e1 = ECAP;
    float4 acc[8];
    const float* sp = &hsl[k * HSTR];
#pragma unroll
    for (int j = 0; j < 8; ++j) acc[j] = *(const float4*)(sp + 4 * j);  // self (pre-scaled)
    unsigned e = e0;
    for (; e + 1 < e1; e += 2) {
      int s0 = eg[e], s1 = eg[e + 1];
      const float* q0 = &hsl[s0 * HSTR];
      const float* q1 = &hsl[s1 * HSTR];
#pragma unroll
      for (int j = 0; j < 8; ++j) {
        float4 a = *(const float4*)(q0 + 4 * j);
        float4 b2 = *(const float4*)(q1 + 4 * j);
        acc[j].x += a.x + b2.x; acc[j].y += a.y + b2.y;
        acc[j].z += a.z + b2.z; acc[j].w += a.w + b2.w;
      }
    }
    if (e < e1) {
      int s0 = eg[e];
      const float* q0 = &hsl[s0 * HSTR];
#pragma unroll
      for (int j = 0; j < 8; ++j) {
        float4 a = *(const float4*)(q0 + 4 * j);
        acc[j].x += a.x; acc[j].y += a.y; acc[j].z += a.z; acc[j].w += a.w;
      }
    }
#pragma unroll
    for (int j = 0; j < 8; ++j) {
      xn[pth][4 * j + 0] = tanh_fast(dk * acc[j].x + bl[j].x);
      xn[pth][4 * j + 1] = tanh_fast(dk * acc[j].y + bl[j].y);
      xn[pth][4 * j + 2] = tanh_fast(dk * acc[j].z + bl[j].z);
      xn[pth][4 * j + 3] = tanh_fast(dk * acc[j].w + bl[j].w);
    }
    // h stored fp16: 32 halves = 4 uint4
    __half* hr = hb16 + (size_t)k * IL + coloff;
#pragma unroll
    for (int j4 = 0; j4 < 4; ++j4) {
      uint4 u;
      u.x = pk2(xn[pth][8 * j4 + 0], xn[pth][8 * j4 + 1]);
      u.y = pk2(xn[pth][8 * j4 + 2], xn[pth][8 * j4 + 3]);
      u.z = pk2(xn[pth][8 * j4 + 4], xn[pth][8 * j4 + 5]);
      u.w = pk2(xn[pth][8 * j4 + 6], xn[pth][8 * j4 + 7]);
      *(uint4*)(hr + 8 * j4) = u;
    }
    if (keyArr) keyArr[k] = xn[pth][31];   // fp32 sort key (col 95)
  }
  __syncthreads();   // all hsl reads done
  if (Wn) {
#pragma unroll
    for (int pth = 0; pth < 2; ++pth) {
      int k = t + pth * 512;
      float dk = dg[k];
      float4 o4[8];
#pragma unroll
      for (int j = 0; j < 8; ++j) { o4[j].x = 0.f; o4[j].y = 0.f; o4[j].z = 0.f; o4[j].w = 0.f; }
#pragma unroll
      for (int c = 0; c < 32; ++c) {
        float xc = xn[pth][c];
        const float4* wr = (const float4*)(Wn + c * 32);   // uniform -> s_load
#pragma unroll
        for (int j4 = 0; j4 < 8; ++j4) {
          float4 w = wr[j4];
          o4[j4].x += xc * w.x; o4[j4].y += xc * w.y;
          o4[j4].z += xc * w.z; o4[j4].w += xc * w.w;
        }
      }
      float* op = &hsl[k * HSTR];
#pragma unroll
      for (int j4 = 0; j4 < 8; ++j4) {
        float4 s;
        s.x = o4[j4].x * dk; s.y = o4[j4].y * dk;
        s.z = o4[j4].z * dk; s.w = o4[j4].w * dk;
        *(float4*)(op + 4 * j4) = s;
      }
    }
    __syncthreads();   // hsl now holds hlin_next * d
  }
}

// ---------------- whole 3-layer GCN: one block per graph, hlin never leaves LDS ----------
__global__ __launch_bounds__(512, 1) void k_gcn(const float* __restrict__ x,
                                             const float* __restrict__ dis,
                                             const unsigned short* __restrict__ esrc16,
                                             const unsigned* __restrict__ dstptr,
                                             const float* __restrict__ W1, const float* __restrict__ b1,
                                             const float* __restrict__ W2, const float* __restrict__ b2,
                                             const float* __restrict__ W3, const float* __restrict__ b3,
                                             __half* __restrict__ h16, float* __restrict__ key) {
  __shared__ float hsl[PP * HSTR];   // 144 KB: [1024 rows][32 data + 4 pad]
  int t = threadIdx.x, g = blockIdx.x;
  const float* dg = dis + (size_t)g * PP;
  const unsigned* dp = dstptr + (size_t)g * (PP + 1);
  const unsigned short* eg = esrc16 + (size_t)g * ECAP;
  __half* hb16 = h16 + (size_t)g * PP * IL;
  float* keyg = key + (size_t)g * PP;

  // pads <- W1 (128x32 = 4096 floats == exactly the pad capacity)
#pragma unroll
  for (int pp = 0; pp < 8; ++pp) {
    int p = t + pp * 512;
    hsl[(p >> 2) * HSTR + 32 + (p & 3)] = W1[p];
  }
  __syncthreads();

  // GEMM1: hsl[row][0..31] = (x_row @ W1) * d_row.  8 rows x 8 cols per thread.
  {
    int cg = t & 3, ng = t >> 2;          // ng 0..127
    int row0 = ng * 8;
    const float* xr = x + ((size_t)g * PP + row0) * FIN;
    float acc[8][8];
#pragma unroll
    for (int r = 0; r < 8; ++r)
#pragma unroll
      for (int j = 0; j < 8; ++j) acc[r][j] = 0.f;
    for (int k4 = 0; k4 < FIN / 4; ++k4) {
      float4 xv[8];
#pragma unroll
      for (int r = 0; r < 8; ++r)
        xv[r] = *(const float4*)(xr + (size_t)r * FIN + k4 * 4);
#pragma unroll
      for (int kk = 0; kk < 4; ++kk) {
        int k = k4 * 4 + kk;
        float4 wa = *(const float4*)&hsl[(k * 8 + cg * 2) * HSTR + 32];
        float4 wb = *(const float4*)&hsl[(k * 8 + cg * 2 + 1) * HSTR + 32];
#pragma unroll
        for (int r = 0; r < 8; ++r) {
          float xk = kk == 0 ? xv[r].x : kk == 1 ? xv[r].y : kk == 2 ? xv[r].z : xv[r].w;
          acc[r][0] += xk * wa.x; acc[r][1] += xk * wa.y;
          acc[r][2] += xk * wa.z; acc[r][3] += xk * wa.w;
          acc[r][4] += xk * wb.x; acc[r][5] += xk * wb.y;
          acc[r][6] += xk * wb.z; acc[r][7] += xk * wb.w;
        }
      }
    }
#pragma unroll
    for (int r = 0; r < 8; ++r) {
      float d = dg[row0 + r];
      float4 s0, s1;
      s0.x = acc[r][0] * d; s0.y = acc[r][1] * d; s0.z = acc[r][2] * d; s0.w = acc[r][3] * d;
      s1.x = acc[r][4] * d; s1.y = acc[r][5] * d; s1.z = acc[r][6] * d; s1.w = acc[r][7] * d;
      *(float4*)&hsl[(row0 + r) * HSTR + cg * 8] = s0;
      *(float4*)&hsl[(row0 + r) * HSTR + cg * 8 + 4] = s1;
    }
  }
  __syncthreads();

  gcn_layer(hsl, dg, dp, eg, b1, 0,  W2, hb16, nullptr, t);
  gcn_layer(hsl, dg, dp, eg, b2, 32, W3, hb16, nullptr, t);
  gcn_layer(hsl, dg, dp, eg, b3, 64, nullptr, hb16, keyg, t);
}

// ---------------- per-graph stable descending sort by fp32 key (bitonic, 512 thr) ---------
__global__ __launch_bounds__(512) void k_sort(const float* __restrict__ keyArr,
                                              unsigned short* __restrict__ rank16) {
  __shared__ float key[PP];
  __shared__ unsigned sidx[PP];
  int t = threadIdx.x, g = blockIdx.x;
  for (int i = t; i < PP; i += 512) {
    key[i] = keyArr[(size_t)g * PP + i];
    sidx[i] = i;
  }
  __syncthreads();
  for (int sz = 2; sz <= PP; sz <<= 1) {
    for (int st = sz >> 1; st > 0; st >>= 1) {
      int i = 2 * t - (t & (st - 1));
      int j = i + st;
      float ki = key[i], kj = key[j];
      unsigned ii = sidx[i], ij = sidx[j];
      bool less_ji = (kj > ki) || (kj == ki && ij < ii);
      bool asc = ((i & sz) == 0);
      if (less_ji == asc) { key[i] = kj; key[j] = ki; sidx[i] = ij; sidx[j] = ii; }
      __syncthreads();
    }
  }
  for (int i = t; i < PP; i += 512) rank16[g * PP + sidx[i]] = (unsigned short)i;
}

// ---------------- position encoding ----------------
__global__ void k_pe(float* __restrict__ pe) {
  int id = blockIdx.x * 256 + threadIdx.x;
  if (id >= PP * 48) return;
  int pos = id / 48, i = id % 48;
  float denom = powf(10000.0f, (2.0f * i) / 96.0f);
  float ang = (float)pos / denom;
  pe[pos * IL + 2 * i] = sinf(ang);
  pe[pos * IL + 2 * i + 1] = cosf(ang);
}

// ---------------- WPE[c][pos][j] = sum_i capsW[c][j][i] * pe[pos][i], fp16 ----------------
__global__ void k_wpe(const float* __restrict__ pe, const float* __restrict__ capsW,
                      __half* __restrict__ wpe) {
  int id = blockIdx.x * 256 + threadIdx.x;
  if (id >= NC * PP * OL) return;
  int j = id & 15;
  int pos = (id >> 4) & 1023;
  int c = id >> 14;
  const float* wr = capsW + (size_t)(c * OL + j) * IL;
  const float* pr = pe + (size_t)pos * IL;
  float a = 0;
#pragma unroll 8
  for (int i = 0; i < IL; ++i) a += wr[i] * pr[i];
  wpe[(((size_t)c << 10) + pos) * 16 + j] = __float2half(a);
}

// ---------------- fused priors MFMA + k-means routing: one block per graph ----------------
// 8 waves x 128 rows; A-frags (h fp16) held in registers for all 10 capsules.
// Per capsule: 24 MFMA/wave -> priors staged in LDS pls[1024][PLSTR] -> +WPE -> routing.
__global__ __launch_bounds__(512, 1) void k_caps(const __half* __restrict__ h16,
                                                 const float* __restrict__ capsW,
                                                 const __half* __restrict__ wpe,
                                                 const unsigned short* __restrict__ rank16,
                                                 float* __restrict__ out) {
  __shared__ float pls[PP * PLSTR];   // 80 KB
  __shared__ float wred[8][17];
  __shared__ float v_l[16];
  int t = threadIdx.x, g = blockIdx.x;
  int wv = t >> 6, lane = t & 63;
  int quad = lane >> 4, l16 = lane & 15;
  const __half* hg = h16 + (size_t)g * PP * IL;
  const unsigned short* rk = rank16 + (size_t)g * PP;

  // A fragments: wave wv owns rows wv*128 .. wv*128+127 (rt blocks of 16)
  half8 afr[8][3];
#pragma unroll
  for (int rt = 0; rt < 8; ++rt) {
    int row = wv * 128 + rt * 16 + l16;
    const char* hr = (const char*)(hg + (size_t)row * IL);
#pragma unroll
    for (int kb = 0; kb < 3; ++kb) {
      uint4 u = *(const uint4*)(hr + kb * 64 + quad * 16);
      afr[rt][kb] = *(half8*)&u;
    }
  }
  int k0 = t, k1 = t + 512;   // routing rows owned by this thread
  int rk0 = rk[k0], rk1 = rk[k1];

  for (int ct = 0; ct < NC; ++ct) {
    // B fragments from capsW (fp32 -> f16)
    half8 bfr[3];
    const float* wr = capsW + (size_t)(ct * 16 + l16) * IL + quad * 8;
#pragma unroll
    for (int kb = 0; kb < 3; ++kb) {
      float4 xx = *(const float4*)(wr + kb * 32);
      float4 yy = *(const float4*)(wr + kb * 32 + 4);
      half8 bb;
      bb[0] = (_Float16)xx.x; bb[1] = (_Float16)xx.y; bb[2] = (_Float16)xx.z; bb[3] = (_Float16)xx.w;
      bb[4] = (_Float16)yy.x; bb[5] = (_Float16)yy.y; bb[6] = (_Float16)yy.z; bb[7] = (_Float16)yy.w;
      bfr[kb] = bb;
    }
#pragma unroll
    for (int rt = 0; rt < 8; ++rt) {
      f32x4 acc = {0.f, 0.f, 0.f, 0.f};
      acc = __builtin_amdgcn_mfma_f32_16x16x32_f16(afr[rt][0], bfr[0], acc, 0, 0, 0);
      acc = __builtin_amdgcn_mfma_f32_16x16x32_f16(afr[rt][1], bfr[1], acc, 0, 0, 0);
      acc = __builtin_amdgcn_mfma_f32_16x16x32_f16(afr[rt][2], bfr[2], acc, 0, 0, 0);
      int rbase = wv * 128 + rt * 16 + quad * 4;
#pragma unroll
      for (int r = 0; r < 4; ++r)
        pls[(rbase + r) * PLSTR + l16] = acc[r];
    }
    __syncthreads();

    // load this thread's 2 rows, add WPE (priors = h@W + W@pe)
    float pr[2][16];
#pragma unroll
    for (int i = 0; i < 2; ++i) {
      int k = i == 0 ? k0 : k1;
      int rkk = i == 0 ? rk0 : rk1;
      const float* pp = &pls[k * PLSTR];
      const __half* wc = wpe + (((size_t)ct << 10) + rkk) * 16;
      uint4 w0 = *(const uint4*)wc;
      uint4 w1 = *(const uint4*)(wc + 8);
      const __half2* pw0 = (const __half2*)&w0;
      const __half2* pw1 = (const __half2*)&w1;
#pragma unroll
      for (int j = 0; j < 4; ++j) {
        float2 f0 = __half22float2(pw0[j]);
        float2 f1 = __half22float2(pw1[j]);
        pr[i][2 * j] = pp[2 * j] + f0.x;
        pr[i][2 * j + 1] = pp[2 * j + 1] + f0.y;
        pr[i][8 + 2 * j] = pp[8 + 2 * j] + f1.x;
        pr[i][8 + 2 * j + 1] = pp[8 + 2 * j + 1] + f1.y;
      }
    }
    // v init = sum of priors
    float vsum[16];
#pragma unroll
    for (int i = 0; i < 16; ++i) vsum[i] = pr[0][i] + pr[1][i];
#pragma unroll
    for (int d = 1; d < 64; d <<= 1)
#pragma unroll
      for (int i = 0; i < 16; ++i) vsum[i] += __shfl_xor(vsum[i], d, 64);
    if (lane == 0) {
#pragma unroll
      for (int i = 0; i < 16; ++i) wred[wv][i] = vsum[i];
    }
    __syncthreads();
    if (t < 16) {
      float s = 0;
#pragma unroll
      for (int w = 0; w < 8; ++w) s += wred[w][t];
      v_l[t] = s;
    }
    __syncthreads();

    for (int it = 0; it < NITER; ++it) {
      float vn[16]; float n2 = 0;
#pragma unroll
      for (int i = 0; i < 16; ++i) { float xv = v_l[i]; vn[i] = xv; n2 += xv * xv; }
      float inv = 1.0f / (sqrtf(n2) + 1e-12f);
#pragma unroll
      for (int i = 0; i < 16; ++i) vn[i] *= inv;
      float lg[2];
#pragma unroll
      for (int i = 0; i < 2; ++i) {
        float a = 0;
#pragma unroll
        for (int j = 0; j < 16; ++j) a += pr[i][j] * vn[j];
        lg[i] = a;
      }
      float mx = fmaxf(lg[0], lg[1]);
#pragma unroll
      for (int d = 1; d < 64; d <<= 1) mx = fmaxf(mx, __shfl_xor(mx, d, 64));
      __syncthreads();   // wred safe to rewrite
      if (lane == 0) wred[wv][16] = mx;
      __syncthreads();
      float gmax = wred[0][16];
#pragma unroll
      for (int w = 1; w < 8; ++w) gmax = fmaxf(gmax, wred[w][16]);
      float es = 0; float eacc[16];
#pragma unroll
      for (int i = 0; i < 16; ++i) eacc[i] = 0.f;
#pragma unroll
      for (int i = 0; i < 2; ++i) {
        float e = __expf(lg[i] - gmax);
        es += e;
#pragma unroll
        for (int j = 0; j < 16; ++j) eacc[j] += e * pr[i][j];
      }
#pragma unroll
      for (int d = 1; d < 64; d <<= 1) {
        es += __shfl_xor(es, d, 64);
#pragma unroll
        for (int i = 0; i < 16; ++i) eacc[i] += __shfl_xor(eacc[i], d, 64);
      }
      __syncthreads();   // gmax consumed by all waves
      if (lane == 0) {
#pragma unroll
        for (int i = 0; i < 16; ++i) wred[wv][i] = eacc[i];
        wred[wv][16] = es;
      }
      __syncthreads();
      if (t < 16) {
        float s = 0, S = 0;
#pragma unroll
        for (int w = 0; w < 8; ++w) { s += wred[w][t]; S += wred[w][16]; }
        v_l[t] = s / S;
      }
      __syncthreads();
    }
    if (t == 0) {
      float n2 = 0;
#pragma unroll
      for (int i = 0; i < 16; ++i) { float xv = v_l[i]; n2 += xv * xv; }
      out[g * NC + ct] = (n2 / (1.0f + n2)) * sqrtf(n2) / sqrtf(n2 + 1e-12f);
    }
    __syncthreads();   // pls/v_l safe to rewrite next capsule
  }
}

extern "C" void kernel_launch(void* const* d_in, const int* in_sizes, int n_in,
                              void* d_out, int out_size, void* d_ws, size_t ws_size,
                              hipStream_t stream) {
  const float* x     = (const float*)d_in[0];
  const int*   ei    = (const int*)d_in[1];
  const float* W1    = (const float*)d_in[3];
  const float* b1    = (const float*)d_in[4];
  const float* W2    = (const float*)d_in[5];
  const float* b2    = (const float*)d_in[6];
  const float* W3    = (const float*)d_in[7];
  const float* b3    = (const float*)d_in[8];
  const float* capsW = (const float*)d_in[9];
  float* out = (float*)d_out;

  char* wp = (char*)d_ws;
  auto alloc = [&](size_t bytes) { char* p = wp; wp += (bytes + 255) & ~(size_t)255; return p; };
  float*    dis    = (float*)alloc((size_t)N_NODES * 4);
  __half*   h16    = (__half*)alloc((size_t)N_NODES * IL * 2);           // 50 MB
  float*    key    = (float*)alloc((size_t)N_NODES * 4);                 // 1 MB
  unsigned* epack  = (unsigned*)alloc((size_t)NE * 4);                   // 16 MB
  unsigned short* esrc16 = (unsigned short*)alloc((size_t)NG * ECAP * 2);// 9 MB
  unsigned* histT  = (unsigned*)alloc((size_t)NCHUNK * NG * 4);          // 1 MB
  unsigned* cbaseT = (unsigned*)alloc((size_t)NCHUNK * NG * 4);          // 1 MB
  unsigned* gtot   = (unsigned*)alloc((size_t)NG * 4);
  unsigned* gbase  = (unsigned*)alloc((size_t)(NG + 1) * 4);
  unsigned* dstptr = (unsigned*)alloc((size_t)NG * (PP + 1) * 4);
  unsigned short* rank16 = (unsigned short*)alloc((size_t)NG * PP * 2);
  float*    pe     = (float*)alloc((size_t)PP * IL * 4);
  __half*   wpe    = (__half*)alloc((size_t)NC * PP * OL * 2);

  k_hist<<<NCHUNK, 256, 0, stream>>>(ei, histT);
  k_scanA<<<NG, 256, 0, stream>>>(histT, cbaseT, gtot);
  k_scanB<<<1, 256, 0, stream>>>(gtot, gbase);
  k_scatter<<<NCHUNK, 256, 0, stream>>>(ei, cbaseT, gbase, epack);
  k_dstsort<<<NG, 256, 0, stream>>>(epack, gbase, esrc16, dstptr);
  k_dis<<<N_NODES / 256, 256, 0, stream>>>(dstptr, dis);
  k_pe<<<(PP * 48) / 256, 256, 0, stream>>>(pe);
  k_wpe<<<(NC * PP * OL) / 256, 256, 0, stream>>>(pe, capsW, wpe);

  k_gcn<<<NG, 512, 0, stream>>>(x, dis, esrc16, dstptr, W1, b1, W2, b2, W3, b3, h16, key);

  k_sort<<<NG, 512, 0, stream>>>(key, rank16);
  k_caps<<<NG, 512, 0, stream>>>(h16, capsW, wpe, rank16, out);
}

// Round 5
// 654.250 us; speedup vs baseline: 1.0035x; 1.0035x over previous
//
#include <hip/hip_runtime.h>
#include <hip/hip_fp16.h>
#include <cstdint>
#include <cstddef>

#define N_NODES   262144
#define NG        256
#define PP        1024
#define NE        4194304
#define FIN       128
#define HH        32
#define NC        10
#define OL        16
#define IL        96
#define NITER     3
#define ECHUNK    4096
#define NCHUNK    (NE/ECHUNK)   // 1024
#define ECAP      18432

typedef _Float16 half8 __attribute__((ext_vector_type(8)));
typedef float f32x4 __attribute__((ext_vector_type(4)));

__device__ __forceinline__ float tanh_fast(float x) {
  float e = __expf(2.0f * x);
  return 1.0f - 2.0f / (e + 1.0f);
}
__device__ __forceinline__ unsigned pk2(float a, float b) {
  __half2 h = __floats2half2_rn(a, b);
  union { __half2 h; unsigned u; } v; v.h = h; return v.u;
}
__device__ __forceinline__ __half2 u2h2(unsigned u) {
  union { unsigned u; __half2 h; } v; v.u = u; return v.h;
}

// swizzled hsl addressing: [1024 rows][32 halves], 16B chunk c -> c ^ ((row>>1)&3).
// bank-group = (row&1, phys-chunk): row mod 8 sweeps all 8 groups -> conflict-free
// random-row ds_read_b128 gather.
__device__ __forceinline__ int hslc(int row, int c) {
  return row * 32 + ((c ^ ((row >> 1) & 3)) << 3);
}
__device__ __forceinline__ int hslh(int row, int halfcol) {
  return hslc(row, halfcol >> 3) + (halfcol & 7);
}

// ---------------- per-chunk per-graph edge histogram (transposed output) ----------------
__global__ void k_hist(const int* __restrict__ ei, unsigned* __restrict__ histT) {
  __shared__ unsigned lh[NG];
  int t = threadIdx.x, b = blockIdx.x;
  lh[t] = 0;
  __syncthreads();
  int base = b * ECHUNK;
  for (int q = t; q < ECHUNK; q += 256) {
    int e = base + q;
    int s = ei[e], d = ei[NE + e];
    if (s != d) atomicAdd(&lh[s >> 10], 1u);
  }
  __syncthreads();
  histT[t * NCHUNK + b] = lh[t];   // [g][ch]
}

// ---------------- per-graph scan over chunks: cbaseT[ch][g] (within-graph excl), gtot[g] ---
__global__ void k_scanA(const unsigned* __restrict__ histT, unsigned* __restrict__ cbaseT,
                        unsigned* __restrict__ gtot) {
  __shared__ unsigned wtot[4];
  int t = threadIdx.x, g = blockIdx.x;
  int lane = t & 63, wv = t >> 6;
  uint4 hv = *(const uint4*)(histT + (size_t)g * NCHUNK + t * 4);
  unsigned s0 = hv.x, s1 = s0 + hv.y, s2 = s1 + hv.z, s3 = s2 + hv.w;
  unsigned tsum = s3, sc = tsum;
  for (int d = 1; d < 64; d <<= 1) {
    unsigned v = __shfl_up(sc, d, 64);
    if (lane >= d) sc += v;
  }
  if (lane == 63) wtot[wv] = sc;
  __syncthreads();
  unsigned woff = 0;
  for (int w = 0; w < wv; ++w) woff += wtot[w];
  unsigned base = woff + sc - tsum;   // exclusive
  cbaseT[(size_t)(t * 4 + 0) * NG + g] = base;
  cbaseT[(size_t)(t * 4 + 1) * NG + g] = base + s0;
  cbaseT[(size_t)(t * 4 + 2) * NG + g] = base + s1;
  cbaseT[(size_t)(t * 4 + 3) * NG + g] = base + s2;
  if (t == 255) gtot[g] = woff + sc;
}

// ---------------- scan of per-graph totals -> gbase[257] ----------------
__global__ void k_scanB(const unsigned* __restrict__ gtot, unsigned* __restrict__ gbase) {
  __shared__ unsigned wtot[4];
  int t = threadIdx.x;
  int lane = t & 63, wv = t >> 6;
  unsigned x = gtot[t], sc = x;
  for (int d = 1; d < 64; d <<= 1) {
    unsigned v = __shfl_up(sc, d, 64);
    if (lane >= d) sc += v;
  }
  if (lane == 63) wtot[wv] = sc;
  __syncthreads();
  unsigned woff = 0;
  for (int w = 0; w < wv; ++w) woff += wtot[w];
  gbase[t] = woff + sc - x;
  if (t == 255) gbase[256] = woff + sc;
}

// ---------------- scatter edges into graph buckets ----------------
__global__ void k_scatter(const int* __restrict__ ei, const unsigned* __restrict__ cbaseT,
                          const unsigned* __restrict__ gbase, unsigned* __restrict__ epack) {
  __shared__ unsigned lcur[NG];
  int t = threadIdx.x, b = blockIdx.x;
  lcur[t] = gbase[t] + cbaseT[(size_t)b * NG + t];
  __syncthreads();
  int base = b * ECHUNK;
  for (int q = t; q < ECHUNK; q += 256) {
    int e = base + q;
    int s = ei[e], d = ei[NE + e];
    if (s != d) {
      int g = s >> 10;
      unsigned pos = atomicAdd(&lcur[g], 1u);
      epack[pos] = (unsigned)(s & 1023) | ((unsigned)(d & 1023) << 10);
    }
  }
}

// ---------------- per-graph counting sort by dst offset -> CSR + u16 src list ------------
__global__ __launch_bounds__(256) void k_dstsort(const unsigned* __restrict__ epack,
                          const unsigned* __restrict__ gbase,
                          unsigned short* __restrict__ esrc16,
                          unsigned* __restrict__ dstptr) {
  __shared__ unsigned shist[PP];
  __shared__ unsigned wsum[256];
  __shared__ unsigned cur[PP];
  int t = threadIdx.x, g = blockIdx.x;
  unsigned e0 = gbase[g], e1 = gbase[g + 1];
  for (int i = t; i < PP; i += 256) shist[i] = 0;
  __syncthreads();
  for (unsigned e = e0 + t; e < e1; e += 256)
    atomicAdd(&shist[(epack[e] >> 10) & 1023], 1u);
  __syncthreads();
  unsigned h0 = shist[4 * t], h1 = shist[4 * t + 1], h2 = shist[4 * t + 2], h3 = shist[4 * t + 3];
  unsigned tsum = h0 + h1 + h2 + h3;
  wsum[t] = tsum;
  __syncthreads();
  for (int off = 1; off < 256; off <<= 1) {
    unsigned v = (t >= off) ? wsum[t - off] : 0u;
    __syncthreads();
    wsum[t] += v;
    __syncthreads();
  }
  unsigned excl = wsum[t] - tsum;
  unsigned c0 = excl, c1 = c0 + h0, c2 = c1 + h1, c3 = c2 + h2;
  cur[4 * t] = c0; cur[4 * t + 1] = c1; cur[4 * t + 2] = c2; cur[4 * t + 3] = c3;
  unsigned* dp = dstptr + (size_t)g * (PP + 1);
  dp[4 * t] = c0; dp[4 * t + 1] = c1; dp[4 * t + 2] = c2; dp[4 * t + 3] = c3;
  if (t == 0) dp[PP] = e1 - e0;
  __syncthreads();
  unsigned short* eg = esrc16 + (size_t)g * ECAP;
  for (unsigned e = e0 + t; e < e1; e += 256) {
    unsigned pk = epack[e];
    unsigned so = pk & 1023, dofs = (pk >> 10) & 1023;
    unsigned pos = atomicAdd(&cur[dofs], 1u);
    if (pos < ECAP) eg[pos] = (unsigned short)so;
  }
}

// ---------------- dis from CSR degrees ----------------
__global__ void k_dis(const unsigned* __restrict__ dstptr, float* __restrict__ dis) {
  int n = blockIdx.x * 256 + threadIdx.x;
  int g = n >> 10, k = n & 1023;
  const unsigned* dp = dstptr + (size_t)g * (PP + 1) + k;
  float deg = (float)(dp[1] - dp[0]);
  dis[n] = 1.0f / sqrtf(deg + 1.0f);
}

// ---------------- one GCN layer: fp16 swizzled-LDS gather (pk_add) -> tanh -> h16;
// optional 32x32 linear (W via s_load) -> overwrite hsl with hlin_next * d (fp16) ---------
__device__ __forceinline__ void gcn_layer(__half* hsl, const float* dg, const unsigned* dp,
                                          const unsigned short* eg, const float* bias,
                                          int coloff, const float* Wn, __half* hb16,
                                          float* keyArr, int t) {
  unsigned xnu[2][16];   // packed tanh outputs (2 nodes x 32 cols as half2)
#pragma unroll
  for (int pth = 0; pth < 2; ++pth) {
    int k = t + pth * 512;
    float dk = dg[k];
    unsigned e0 = dp[k], e1 = dp[k + 1];
    if (e1 > (unsigned)ECAP) e1 = ECAP;
    __half2 acc2[16];
    // self term (hsl rows are pre-scaled by d)
    {
      uint4 u0 = *(const uint4*)&hsl[hslc(k, 0)];
      uint4 u1 = *(const uint4*)&hsl[hslc(k, 1)];
      uint4 u2 = *(const uint4*)&hsl[hslc(k, 2)];
      uint4 u3 = *(const uint4*)&hsl[hslc(k, 3)];
      acc2[0] = u2h2(u0.x); acc2[1] = u2h2(u0.y); acc2[2] = u2h2(u0.z); acc2[3] = u2h2(u0.w);
      acc2[4] = u2h2(u1.x); acc2[5] = u2h2(u1.y); acc2[6] = u2h2(u1.z); acc2[7] = u2h2(u1.w);
      acc2[8] = u2h2(u2.x); acc2[9] = u2h2(u2.y); acc2[10] = u2h2(u2.z); acc2[11] = u2h2(u2.w);
      acc2[12] = u2h2(u3.x); acc2[13] = u2h2(u3.y); acc2[14] = u2h2(u3.z); acc2[15] = u2h2(u3.w);
    }
    unsigned e = e0;
    for (; e + 1 < e1; e += 2) {
      int s0 = eg[e], s1 = eg[e + 1];
      uint4 a0 = *(const uint4*)&hsl[hslc(s0, 0)];
      uint4 a1 = *(const uint4*)&hsl[hslc(s0, 1)];
      uint4 a2 = *(const uint4*)&hsl[hslc(s0, 2)];
      uint4 a3 = *(const uint4*)&hsl[hslc(s0, 3)];
      uint4 b0 = *(const uint4*)&hsl[hslc(s1, 0)];
      uint4 b1 = *(const uint4*)&hsl[hslc(s1, 1)];
      uint4 b2 = *(const uint4*)&hsl[hslc(s1, 2)];
      uint4 b3 = *(const uint4*)&hsl[hslc(s1, 3)];
      acc2[0] = __hadd2(acc2[0], __hadd2(u2h2(a0.x), u2h2(b0.x)));
      acc2[1] = __hadd2(acc2[1], __hadd2(u2h2(a0.y), u2h2(b0.y)));
      acc2[2] = __hadd2(acc2[2], __hadd2(u2h2(a0.z), u2h2(b0.z)));
      acc2[3] = __hadd2(acc2[3], __hadd2(u2h2(a0.w), u2h2(b0.w)));
      acc2[4] = __hadd2(acc2[4], __hadd2(u2h2(a1.x), u2h2(b1.x)));
      acc2[5] = __hadd2(acc2[5], __hadd2(u2h2(a1.y), u2h2(b1.y)));
      acc2[6] = __hadd2(acc2[6], __hadd2(u2h2(a1.z), u2h2(b1.z)));
      acc2[7] = __hadd2(acc2[7], __hadd2(u2h2(a1.w), u2h2(b1.w)));
      acc2[8] = __hadd2(acc2[8], __hadd2(u2h2(a2.x), u2h2(b2.x)));
      acc2[9] = __hadd2(acc2[9], __hadd2(u2h2(a2.y), u2h2(b2.y)));
      acc2[10] = __hadd2(acc2[10], __hadd2(u2h2(a2.z), u2h2(b2.z)));
      acc2[11] = __hadd2(acc2[11], __hadd2(u2h2(a2.w), u2h2(b2.w)));
      acc2[12] = __hadd2(acc2[12], __hadd2(u2h2(a3.x), u2h2(b3.x)));
      acc2[13] = __hadd2(acc2[13], __hadd2(u2h2(a3.y), u2h2(b3.y)));
      acc2[14] = __hadd2(acc2[14], __hadd2(u2h2(a3.z), u2h2(b3.z)));
      acc2[15] = __hadd2(acc2[15], __hadd2(u2h2(a3.w), u2h2(b3.w)));
    }
    if (e < e1) {
      int s0 = eg[e];
      uint4 a0 = *(const uint4*)&hsl[hslc(s0, 0)];
      uint4 a1 = *(const uint4*)&hsl[hslc(s0, 1)];
      uint4 a2 = *(const uint4*)&hsl[hslc(s0, 2)];
      uint4 a3 = *(const uint4*)&hsl[hslc(s0, 3)];
      acc2[0] = __hadd2(acc2[0], u2h2(a0.x)); acc2[1] = __hadd2(acc2[1], u2h2(a0.y));
      acc2[2] = __hadd2(acc2[2], u2h2(a0.z)); acc2[3] = __hadd2(acc2[3], u2h2(a0.w));
      acc2[4] = __hadd2(acc2[4], u2h2(a1.x)); acc2[5] = __hadd2(acc2[5], u2h2(a1.y));
      acc2[6] = __hadd2(acc2[6], u2h2(a1.z)); acc2[7] = __hadd2(acc2[7], u2h2(a1.w));
      acc2[8] = __hadd2(acc2[8], u2h2(a2.x)); acc2[9] = __hadd2(acc2[9], u2h2(a2.y));
      acc2[10] = __hadd2(acc2[10], u2h2(a2.z)); acc2[11] = __hadd2(acc2[11], u2h2(a2.w));
      acc2[12] = __hadd2(acc2[12], u2h2(a3.x)); acc2[13] = __hadd2(acc2[13], u2h2(a3.y));
      acc2[14] = __hadd2(acc2[14], u2h2(a3.z)); acc2[15] = __hadd2(acc2[15], u2h2(a3.w));
    }
    // tanh + pack (bias via s_load, uniform address)
    float lastv = 0.f;
#pragma unroll
    for (int i = 0; i < 16; ++i) {
      float2 f = __half22float2(acc2[i]);
      float a0 = tanh_fast(dk * f.x + bias[2 * i]);
      float a1 = tanh_fast(dk * f.y + bias[2 * i + 1]);
      xnu[pth][i] = pk2(a0, a1);
      if (i == 15) lastv = a1;
    }
    __half* hr = hb16 + (size_t)k * IL + coloff;
    uint4 h0, h1;
    h0.x = xnu[pth][0]; h0.y = xnu[pth][1]; h0.z = xnu[pth][2]; h0.w = xnu[pth][3];
    h1.x = xnu[pth][4]; h1.y = xnu[pth][5]; h1.z = xnu[pth][6]; h1.w = xnu[pth][7];
    ((uint4*)hr)[0] = h0;
    ((uint4*)hr)[1] = h1;
    uint4 h2, h3;
    h2.x = xnu[pth][8]; h2.y = xnu[pth][9]; h2.z = xnu[pth][10]; h2.w = xnu[pth][11];
    h3.x = xnu[pth][12]; h3.y = xnu[pth][13]; h3.z = xnu[pth][14]; h3.w = xnu[pth][15];
    ((uint4*)hr)[2] = h2;
    ((uint4*)hr)[3] = h3;
    if (keyArr) keyArr[k] = lastv;   // fp32 sort key (col 95)
  }
  __syncthreads();   // all hsl reads done
  if (Wn) {
#pragma unroll
    for (int pth = 0; pth < 2; ++pth) {
      int k = t + pth * 512;
      float dk = dg[k];
      float4 o4[8];
#pragma unroll
      for (int j = 0; j < 8; ++j) { o4[j].x = 0.f; o4[j].y = 0.f; o4[j].z = 0.f; o4[j].w = 0.f; }
#pragma unroll
      for (int c2 = 0; c2 < 16; ++c2) {
        float2 xc = __half22float2(u2h2(xnu[pth][c2]));
        const float4* wr0 = (const float4*)(Wn + (2 * c2) * 32);       // uniform -> s_load
        const float4* wr1 = (const float4*)(Wn + (2 * c2 + 1) * 32);
#pragma unroll
        for (int j4 = 0; j4 < 8; ++j4) {
          float4 w0 = wr0[j4], w1 = wr1[j4];
          o4[j4].x += xc.x * w0.x + xc.y * w1.x;
          o4[j4].y += xc.x * w0.y + xc.y * w1.y;
          o4[j4].z += xc.x * w0.z + xc.y * w1.z;
          o4[j4].w += xc.x * w0.w + xc.y * w1.w;
        }
      }
#pragma unroll
      for (int c = 0; c < 4; ++c) {
        uint4 u;
        u.x = pk2(o4[2 * c].x * dk, o4[2 * c].y * dk);
        u.y = pk2(o4[2 * c].z * dk, o4[2 * c].w * dk);
        u.z = pk2(o4[2 * c + 1].x * dk, o4[2 * c + 1].y * dk);
        u.w = pk2(o4[2 * c + 1].z * dk, o4[2 * c + 1].w * dk);
        *(uint4*)&hsl[hslc(k, c)] = u;
      }
    }
    __syncthreads();   // hsl now holds hlin_next * d
  }
}

// ---------------- whole 3-layer GCN: 64 KB fp16 LDS -> 2 blocks/CU; GEMM1 via MFMA --------
__global__ __launch_bounds__(512, 4) void k_gcn(const float* __restrict__ x,
                                             const float* __restrict__ dis,
                                             const unsigned short* __restrict__ esrc16,
                                             const unsigned* __restrict__ dstptr,
                                             const float* __restrict__ W1, const float* __restrict__ b1,
                                             const float* __restrict__ W2, const float* __restrict__ b2,
                                             const float* __restrict__ W3, const float* __restrict__ b3,
                                             __half* __restrict__ h16, float* __restrict__ key) {
  __shared__ __half hsl[PP * 32];   // 64 KB swizzled fp16
  int t = threadIdx.x, g = blockIdx.x;
  const float* dg = dis + (size_t)g * PP;
  const unsigned* dp = dstptr + (size_t)g * (PP + 1);
  const unsigned short* eg = esrc16 + (size_t)g * ECAP;
  __half* hb16 = h16 + (size_t)g * PP * IL;
  float* keyg = key + (size_t)g * PP;

  // GEMM1 via MFMA 16x16x32 f16: hsl[row][c] = (x_row @ W1)[c] * d_row
  {
    int wv = t >> 6, lane = t & 63, quad = lane >> 4, l16 = lane & 15;
    half8 bfr[2][4];
#pragma unroll
    for (int nt = 0; nt < 2; ++nt)
#pragma unroll
      for (int kf = 0; kf < 4; ++kf) {
        half8 bb;
#pragma unroll
        for (int j = 0; j < 8; ++j)
          bb[j] = (_Float16)W1[(kf * 32 + quad * 8 + j) * HH + nt * 16 + l16];
        bfr[nt][kf] = bb;
      }
#pragma unroll
    for (int rt = 0; rt < 8; ++rt) {
      int row = wv * 128 + rt * 16 + l16;
      const float* xr = x + ((size_t)g * PP + row) * FIN;
      half8 af[4];
#pragma unroll
      for (int kf = 0; kf < 4; ++kf) {
        float4 xa = *(const float4*)(xr + kf * 32 + quad * 8);
        float4 xb = *(const float4*)(xr + kf * 32 + quad * 8 + 4);
        half8 a;
        a[0] = (_Float16)xa.x; a[1] = (_Float16)xa.y; a[2] = (_Float16)xa.z; a[3] = (_Float16)xa.w;
        a[4] = (_Float16)xb.x; a[5] = (_Float16)xb.y; a[6] = (_Float16)xb.z; a[7] = (_Float16)xb.w;
        af[kf] = a;
      }
      int rb = wv * 128 + rt * 16 + quad * 4;
      float dv0 = dg[rb], dv1 = dg[rb + 1], dv2 = dg[rb + 2], dv3 = dg[rb + 3];
#pragma unroll
      for (int nt = 0; nt < 2; ++nt) {
        f32x4 acc = {0.f, 0.f, 0.f, 0.f};
        acc = __builtin_amdgcn_mfma_f32_16x16x32_f16(af[0], bfr[nt][0], acc, 0, 0, 0);
        acc = __builtin_amdgcn_mfma_f32_16x16x32_f16(af[1], bfr[nt][1], acc, 0, 0, 0);
        acc = __builtin_amdgcn_mfma_f32_16x16x32_f16(af[2], bfr[nt][2], acc, 0, 0, 0);
        acc = __builtin_amdgcn_mfma_f32_16x16x32_f16(af[3], bfr[nt][3], acc, 0, 0, 0);
        int col = nt * 16 + l16;
        hsl[hslh(rb + 0, col)] = __float2half(acc[0] * dv0);
        hsl[hslh(rb + 1, col)] = __float2half(acc[1] * dv1);
        hsl[hslh(rb + 2, col)] = __float2half(acc[2] * dv2);
        hsl[hslh(rb + 3, col)] = __float2half(acc[3] * dv3);
      }
    }
  }
  __syncthreads();

  gcn_layer(hsl, dg, dp, eg, b1, 0,  W2, hb16, nullptr, t);
  gcn_layer(hsl, dg, dp, eg, b2, 32, W3, hb16, nullptr, t);
  gcn_layer(hsl, dg, dp, eg, b3, 64, nullptr, hb16, keyg, t);
}

// ---------------- per-graph stable descending sort by fp32 key (bitonic, 512 thr) ---------
__global__ __launch_bounds__(512) void k_sort(const float* __restrict__ keyArr,
                                              unsigned short* __restrict__ rank16) {
  __shared__ float key[PP];
  __shared__ unsigned sidx[PP];
  int t = threadIdx.x, g = blockIdx.x;
  for (int i = t; i < PP; i += 512) {
    key[i] = keyArr[(size_t)g * PP + i];
    sidx[i] = i;
  }
  __syncthreads();
  for (int sz = 2; sz <= PP; sz <<= 1) {
    for (int st = sz >> 1; st > 0; st >>= 1) {
      int i = 2 * t - (t & (st - 1));
      int j = i + st;
      float ki = key[i], kj = key[j];
      unsigned ii = sidx[i], ij = sidx[j];
      bool less_ji = (kj > ki) || (kj == ki && ij < ii);
      bool asc = ((i & sz) == 0);
      if (less_ji == asc) { key[i] = kj; key[j] = ki; sidx[i] = ij; sidx[j] = ii; }
      __syncthreads();
    }
  }
  for (int i = t; i < PP; i += 512) rank16[g * PP + sidx[i]] = (unsigned short)i;
}

// ---------------- position encoding ----------------
__global__ void k_pe(float* __restrict__ pe) {
  int id = blockIdx.x * 256 + threadIdx.x;
  if (id >= PP * 48) return;
  int pos = id / 48, i = id % 48;
  float denom = powf(10000.0f, (2.0f * i) / 96.0f);
  float ang = (float)pos / denom;
  pe[pos * IL + 2 * i] = sinf(ang);
  pe[pos * IL + 2 * i + 1] = cosf(ang);
}

// ---------------- WPE[c][pos][j] = sum_i capsW[c][j][i] * pe[pos][i], fp16 ----------------
__global__ void k_wpe(const float* __restrict__ pe, const float* __restrict__ capsW,
                      __half* __restrict__ wpe) {
  int id = blockIdx.x * 256 + threadIdx.x;
  if (id >= NC * PP * OL) return;
  int j = id & 15;
  int pos = (id >> 4) & 1023;
  int c = id >> 14;
  const float* wr = capsW + (size_t)(c * OL + j) * IL;
  const float* pr = pe + (size_t)pos * IL;
  float a = 0;
#pragma unroll 8
  for (int i = 0; i < IL; ++i) a += wr[i] * pr[i];
  wpe[(((size_t)c << 10) + pos) * 16 + j] = __float2half(a);
}

// ---------------- priors GEMM via MFMA f16: Pc[g][c][k][16] = h16[k] @ capsW[c*16+j] -------
__global__ __launch_bounds__(256) void k_pgemm(const __half* __restrict__ h16,
                                               const float* __restrict__ capsW,
                                               __half* __restrict__ Pc) {
  int t = threadIdx.x, b = blockIdx.x;
  int g = b >> 2;
  int wv = t >> 6, lane = t & 63;
  int quad = lane >> 4, l16 = lane & 15;
  half8 afr[4][3];
#pragma unroll
  for (int rt = 0; rt < 4; ++rt) {
    int row = b * 256 + wv * 64 + rt * 16 + l16;
    const __half* hr = h16 + (size_t)row * IL + quad * 8;
#pragma unroll
    for (int kb = 0; kb < 3; ++kb) {
      uint4 u = *(const uint4*)(hr + kb * 32);
      afr[rt][kb] = __builtin_bit_cast(half8, u);
    }
  }
  int krow_base = (b & 3) * 256 + wv * 64;
  for (int ct = 0; ct < NC; ++ct) {
    half8 bfr[3];
    const float* wr = capsW + (size_t)(ct * 16 + l16) * IL + quad * 8;
#pragma unroll
    for (int kb = 0; kb < 3; ++kb) {
      float4 xx = *(const float4*)(wr + kb * 32);
      float4 yy = *(const float4*)(wr + kb * 32 + 4);
      half8 bb;
      bb[0] = (_Float16)xx.x; bb[1] = (_Float16)xx.y; bb[2] = (_Float16)xx.z; bb[3] = (_Float16)xx.w;
      bb[4] = (_Float16)yy.x; bb[5] = (_Float16)yy.y; bb[6] = (_Float16)yy.z; bb[7] = (_Float16)yy.w;
      bfr[kb] = bb;
    }
#pragma unroll
    for (int rt = 0; rt < 4; ++rt) {
      f32x4 acc = {0.f, 0.f, 0.f, 0.f};
      acc = __builtin_amdgcn_mfma_f32_16x16x32_f16(afr[rt][0], bfr[0], acc, 0, 0, 0);
      acc = __builtin_amdgcn_mfma_f32_16x16x32_f16(afr[rt][1], bfr[1], acc, 0, 0, 0);
      acc = __builtin_amdgcn_mfma_f32_16x16x32_f16(afr[rt][2], bfr[2], acc, 0, 0, 0);
      int krow = krow_base + rt * 16;
      __half* po = Pc + ((((size_t)g * NC + ct) << 10) + krow) * 16 + l16;
#pragma unroll
      for (int r = 0; r < 4; ++r)
        po[(quad * 4 + r) * 16] = __float2half(acc[r]);
    }
  }
}

// ---------------- routing: one block per (graph, capsule), P rows in registers ----------------
__global__ __launch_bounds__(256) void k_route2(const __half* __restrict__ Pc,
                                                const __half* __restrict__ wpe,
                                                const unsigned short* __restrict__ rank16,
                                                float* __restrict__ out) {
  __shared__ float v_l[16];
  __shared__ float wred[4][17];
  int t = threadIdx.x;
  int gc = blockIdx.x;
  int g = gc / NC, c = gc - g * NC;
  int lane = t & 63, wv = t >> 6;
  const __half* pg = Pc + ((size_t)gc << 10) * 16;
  const unsigned short* rk = rank16 + (size_t)g * PP;
  const __half* wc = wpe + ((size_t)c << 10) * 16;
  float pr[4][16];
  float vsum[16];
#pragma unroll
  for (int i = 0; i < 16; ++i) vsum[i] = 0.f;
#pragma unroll
  for (int r = 0; r < 4; ++r) {
    int k = t + r * 256;
    uint4 a0 = *(const uint4*)(pg + (size_t)k * 16);
    uint4 a1 = *(const uint4*)(pg + (size_t)k * 16 + 8);
    int rkk = rk[k];
    uint4 b0 = *(const uint4*)(wc + (size_t)rkk * 16);
    uint4 b1 = *(const uint4*)(wc + (size_t)rkk * 16 + 8);
    const __half2* pa0 = (const __half2*)&a0; const __half2* pa1 = (const __half2*)&a1;
    const __half2* pb0 = (const __half2*)&b0; const __half2* pb1 = (const __half2*)&b1;
#pragma unroll
    for (int j = 0; j < 4; ++j) {
      float2 fa = __half22float2(pa0[j]); float2 fb = __half22float2(pb0[j]);
      pr[r][2 * j] = fa.x + fb.x; pr[r][2 * j + 1] = fa.y + fb.y;
      float2 fa1 = __half22float2(pa1[j]); float2 fb1 = __half22float2(pb1[j]);
      pr[r][8 + 2 * j] = fa1.x + fb1.x; pr[r][8 + 2 * j + 1] = fa1.y + fb1.y;
    }
#pragma unroll
    for (int i = 0; i < 16; ++i) vsum[i] += pr[r][i];
  }
#pragma unroll
  for (int d = 1; d < 64; d <<= 1)
#pragma unroll
    for (int i = 0; i < 16; ++i) vsum[i] += __shfl_xor(vsum[i], d, 64);
  if (lane == 0) {
#pragma unroll
    for (int i = 0; i < 16; ++i) wred[wv][i] = vsum[i];
  }
  __syncthreads();
  if (t < 16) v_l[t] = wred[0][t] + wred[1][t] + wred[2][t] + wred[3][t];
  __syncthreads();
  for (int it = 0; it < NITER; ++it) {
    float vn[16]; float n2 = 0;
#pragma unroll
    for (int i = 0; i < 16; ++i) { float x = v_l[i]; vn[i] = x; n2 += x * x; }
    float inv = 1.0f / (sqrtf(n2) + 1e-12f);
#pragma unroll
    for (int i = 0; i < 16; ++i) vn[i] *= inv;
    float lg[4];
#pragma unroll
    for (int r = 0; r < 4; ++r) {
      float a = 0;
#pragma unroll
      for (int i = 0; i < 16; ++i) a += pr[r][i] * vn[i];
      lg[r] = a;
    }
    float mx = fmaxf(fmaxf(lg[0], lg[1]), fmaxf(lg[2], lg[3]));
#pragma unroll
    for (int d = 1; d < 64; d <<= 1) mx = fmaxf(mx, __shfl_xor(mx, d, 64));
    __syncthreads();   // wred safe to rewrite
    if (lane == 0) wred[wv][16] = mx;
    __syncthreads();
    float gmax = fmaxf(fmaxf(wred[0][16], wred[1][16]), fmaxf(wred[2][16], wred[3][16]));
    float es = 0; float eacc[16];
#pragma unroll
    for (int i = 0; i < 16; ++i) eacc[i] = 0.f;
#pragma unroll
    for (int r = 0; r < 4; ++r) {
      float e = __expf(lg[r] - gmax);
      es += e;
#pragma unroll
      for (int i = 0; i < 16; ++i) eacc[i] += e * pr[r][i];
    }
#pragma unroll
    for (int d = 1; d < 64; d <<= 1) {
      es += __shfl_xor(es, d, 64);
#pragma unroll
      for (int i = 0; i < 16; ++i) eacc[i] += __shfl_xor(eacc[i], d, 64);
    }
    __syncthreads();   // gmax consumed by all waves
    if (lane == 0) {
#pragma unroll
      for (int i = 0; i < 16; ++i) wred[wv][i] = eacc[i];
      wred[wv][16] = es;
    }
    __syncthreads();
    if (t < 16) {
      float s = wred[0][t] + wred[1][t] + wred[2][t] + wred[3][t];
      float S = wred[0][16] + wred[1][16] + wred[2][16] + wred[3][16];
      v_l[t] = s / S;
    }
    __syncthreads();
  }
  if (t == 0) {
    float n2 = 0;
#pragma unroll
    for (int i = 0; i < 16; ++i) { float x = v_l[i]; n2 += x * x; }
    out[gc] = (n2 / (1.0f + n2)) * sqrtf(n2) / sqrtf(n2 + 1e-12f);
  }
}

extern "C" void kernel_launch(void* const* d_in, const int* in_sizes, int n_in,
                              void* d_out, int out_size, void* d_ws, size_t ws_size,
                              hipStream_t stream) {
  const float* x     = (const float*)d_in[0];
  const int*   ei    = (const int*)d_in[1];
  const float* W1    = (const float*)d_in[3];
  const float* b1    = (const float*)d_in[4];
  const float* W2    = (const float*)d_in[5];
  const float* b2    = (const float*)d_in[6];
  const float* W3    = (const float*)d_in[7];
  const float* b3    = (const float*)d_in[8];
  const float* capsW = (const float*)d_in[9];
  float* out = (float*)d_out;

  char* wp = (char*)d_ws;
  auto alloc = [&](size_t bytes) { char* p = wp; wp += (bytes + 255) & ~(size_t)255; return p; };
  float*    dis    = (float*)alloc((size_t)N_NODES * 4);
  __half*   h16    = (__half*)alloc((size_t)N_NODES * IL * 2);           // 50 MB
  float*    key    = (float*)alloc((size_t)N_NODES * 4);                 // 1 MB
  // --- union region (later fully overlaid by Pc, 80 MiB):
  // [epack 16M] [esrc16 9M] [histT 1M] [cbaseT 1M] — all dead before Pc is written
  char*     ureg   = wp;
  unsigned* epack  = (unsigned*)alloc((size_t)NE * 4);                   // 16 MB
  unsigned short* esrc16 = (unsigned short*)alloc((size_t)NG * ECAP * 2);// 9 MB
  unsigned* histT  = (unsigned*)alloc((size_t)NCHUNK * NG * 4);          // 1 MB
  unsigned* cbaseT = (unsigned*)alloc((size_t)NCHUNK * NG * 4);          // 1 MB
  const size_t PC_BYTES = (size_t)NG * NC * PP * 16 * 2;                 // 80 MiB
  if ((size_t)(wp - ureg) < PC_BYTES) wp = ureg + ((PC_BYTES + 255) & ~(size_t)255);
  __half*   Pc     = (__half*)ureg;                                      // overlays union
  unsigned* gtot   = (unsigned*)alloc((size_t)NG * 4);
  unsigned* gbase  = (unsigned*)alloc((size_t)(NG + 1) * 4);
  unsigned* dstptr = (unsigned*)alloc((size_t)NG * (PP + 1) * 4);
  unsigned short* rank16 = (unsigned short*)alloc((size_t)NG * PP * 2);
  float*    pe     = (float*)alloc((size_t)PP * IL * 4);
  __half*   wpe    = (__half*)alloc((size_t)NC * PP * OL * 2);

  k_hist<<<NCHUNK, 256, 0, stream>>>(ei, histT);
  k_scanA<<<NG, 256, 0, stream>>>(histT, cbaseT, gtot);
  k_scanB<<<1, 256, 0, stream>>>(gtot, gbase);
  k_scatter<<<NCHUNK, 256, 0, stream>>>(ei, cbaseT, gbase, epack);
  k_dstsort<<<NG, 256, 0, stream>>>(epack, gbase, esrc16, dstptr);
  k_dis<<<N_NODES / 256, 256, 0, stream>>>(dstptr, dis);
  k_pe<<<(PP * 48) / 256, 256, 0, stream>>>(pe);
  k_wpe<<<(NC * PP * OL) / 256, 256, 0, stream>>>(pe, capsW, wpe);

  k_gcn<<<NG, 512, 0, stream>>>(x, dis, esrc16, dstptr, W1, b1, W2, b2, W3, b3, h16, key);

  k_sort<<<NG, 512, 0, stream>>>(key, rank16);
  k_pgemm<<<N_NODES / 256, 256, 0, stream>>>(h16, capsW, Pc);   // Pc overlays dead buffers
  k_route2<<<NG * NC, 256, 0, stream>>>(Pc, wpe, rank16, out);
}

// Round 6
// 564.719 us; speedup vs baseline: 1.1626x; 1.1585x over previous
//
#include <hip/hip_runtime.h>
#include <hip/hip_fp16.h>
#include <cstdint>
#include <cstddef>

#define N_NODES   262144
#define NG        256
#define PP        1024
#define NE        4194304
#define FIN       128
#define HH        32
#define NC        10
#define OL        16
#define IL        96
#define NITER     3
#define ECHUNK    4096
#define NCHUNK    (NE/ECHUNK)   // 1024
#define ECAP      18432

typedef _Float16 half8 __attribute__((ext_vector_type(8)));
typedef float f32x4 __attribute__((ext_vector_type(4)));

__device__ __forceinline__ float tanh_fast(float x) {
  float e = __expf(2.0f * x);
  return 1.0f - 2.0f / (e + 1.0f);
}
__device__ __forceinline__ unsigned pk2(float a, float b) {
  __half2 h = __floats2half2_rn(a, b);
  union { __half2 h; unsigned u; } v; v.h = h; return v.u;
}
__device__ __forceinline__ __half2 u2h2(unsigned u) {
  union { unsigned u; __half2 h; } v; v.u = u; return v.h;
}

// swizzled hsl addressing: [1024 rows][32 halves], 16B chunk c -> c ^ ((row>>1)&3).
// byte-group of a chunk = (4*row + c') mod 8 with c' = c ^ ((row>>1)&3):
// fixed c, random row -> uniform over all 8 b128 bank-groups.
__device__ __forceinline__ int hslc(int row, int c) {
  return row * 32 + ((c ^ ((row >> 1) & 3)) << 3);
}

// ---------------- per-chunk per-graph edge histogram (transposed output) ----------------
__global__ void k_hist(const int* __restrict__ ei, unsigned* __restrict__ histT) {
  __shared__ unsigned lh[NG];
  int t = threadIdx.x, b = blockIdx.x;
  lh[t] = 0;
  __syncthreads();
  int base = b * ECHUNK;
  for (int q = t; q < ECHUNK; q += 256) {
    int e = base + q;
    int s = ei[e], d = ei[NE + e];
    if (s != d) atomicAdd(&lh[s >> 10], 1u);
  }
  __syncthreads();
  histT[t * NCHUNK + b] = lh[t];   // [g][ch]
}

// ---------------- per-graph scan over chunks: cbaseT[ch][g] (within-graph excl), gtot[g] ---
__global__ void k_scanA(const unsigned* __restrict__ histT, unsigned* __restrict__ cbaseT,
                        unsigned* __restrict__ gtot) {
  __shared__ unsigned wtot[4];
  int t = threadIdx.x, g = blockIdx.x;
  int lane = t & 63, wv = t >> 6;
  uint4 hv = *(const uint4*)(histT + (size_t)g * NCHUNK + t * 4);
  unsigned s0 = hv.x, s1 = s0 + hv.y, s2 = s1 + hv.z, s3 = s2 + hv.w;
  unsigned tsum = s3, sc = tsum;
  for (int d = 1; d < 64; d <<= 1) {
    unsigned v = __shfl_up(sc, d, 64);
    if (lane >= d) sc += v;
  }
  if (lane == 63) wtot[wv] = sc;
  __syncthreads();
  unsigned woff = 0;
  for (int w = 0; w < wv; ++w) woff += wtot[w];
  unsigned base = woff + sc - tsum;   // exclusive
  cbaseT[(size_t)(t * 4 + 0) * NG + g] = base;
  cbaseT[(size_t)(t * 4 + 1) * NG + g] = base + s0;
  cbaseT[(size_t)(t * 4 + 2) * NG + g] = base + s1;
  cbaseT[(size_t)(t * 4 + 3) * NG + g] = base + s2;
  if (t == 255) gtot[g] = woff + sc;
}

// ---------------- scan of per-graph totals -> gbase[257] ----------------
__global__ void k_scanB(const unsigned* __restrict__ gtot, unsigned* __restrict__ gbase) {
  __shared__ unsigned wtot[4];
  int t = threadIdx.x;
  int lane = t & 63, wv = t >> 6;
  unsigned x = gtot[t], sc = x;
  for (int d = 1; d < 64; d <<= 1) {
    unsigned v = __shfl_up(sc, d, 64);
    if (lane >= d) sc += v;
  }
  if (lane == 63) wtot[wv] = sc;
  __syncthreads();
  unsigned woff = 0;
  for (int w = 0; w < wv; ++w) woff += wtot[w];
  gbase[t] = woff + sc - x;
  if (t == 255) gbase[256] = woff + sc;
}

// ---------------- scatter edges into graph buckets ----------------
__global__ void k_scatter(const int* __restrict__ ei, const unsigned* __restrict__ cbaseT,
                          const unsigned* __restrict__ gbase, unsigned* __restrict__ epack) {
  __shared__ unsigned lcur[NG];
  int t = threadIdx.x, b = blockIdx.x;
  lcur[t] = gbase[t] + cbaseT[(size_t)b * NG + t];
  __syncthreads();
  int base = b * ECHUNK;
  for (int q = t; q < ECHUNK; q += 256) {
    int e = base + q;
    int s = ei[e], d = ei[NE + e];
    if (s != d) {
      int g = s >> 10;
      unsigned pos = atomicAdd(&lcur[g], 1u);
      epack[pos] = (unsigned)(s & 1023) | ((unsigned)(d & 1023) << 10);
    }
  }
}

// ---------------- per-graph counting sort by dst offset -> CSR + u16 src list ------------
__global__ __launch_bounds__(256) void k_dstsort(const unsigned* __restrict__ epack,
                          const unsigned* __restrict__ gbase,
                          unsigned short* __restrict__ esrc16,
                          unsigned* __restrict__ dstptr) {
  __shared__ unsigned shist[PP];
  __shared__ unsigned wsum[256];
  __shared__ unsigned cur[PP];
  int t = threadIdx.x, g = blockIdx.x;
  unsigned e0 = gbase[g], e1 = gbase[g + 1];
  for (int i = t; i < PP; i += 256) shist[i] = 0;
  __syncthreads();
  for (unsigned e = e0 + t; e < e1; e += 256)
    atomicAdd(&shist[(epack[e] >> 10) & 1023], 1u);
  __syncthreads();
  unsigned h0 = shist[4 * t], h1 = shist[4 * t + 1], h2 = shist[4 * t + 2], h3 = shist[4 * t + 3];
  unsigned tsum = h0 + h1 + h2 + h3;
  wsum[t] = tsum;
  __syncthreads();
  for (int off = 1; off < 256; off <<= 1) {
    unsigned v = (t >= off) ? wsum[t - off] : 0u;
    __syncthreads();
    wsum[t] += v;
    __syncthreads();
  }
  unsigned excl = wsum[t] - tsum;
  unsigned c0 = excl, c1 = c0 + h0, c2 = c1 + h1, c3 = c2 + h2;
  cur[4 * t] = c0; cur[4 * t + 1] = c1; cur[4 * t + 2] = c2; cur[4 * t + 3] = c3;
  unsigned* dp = dstptr + (size_t)g * (PP + 1);
  dp[4 * t] = c0; dp[4 * t + 1] = c1; dp[4 * t + 2] = c2; dp[4 * t + 3] = c3;
  if (t == 0) dp[PP] = e1 - e0;
  __syncthreads();
  unsigned short* eg = esrc16 + (size_t)g * ECAP;
  for (unsigned e = e0 + t; e < e1; e += 256) {
    unsigned pk = epack[e];
    unsigned so = pk & 1023, dofs = (pk >> 10) & 1023;
    unsigned pos = atomicAdd(&cur[dofs], 1u);
    if (pos < ECAP) eg[pos] = (unsigned short)so;
  }
}

// ---------------- dis from CSR degrees ----------------
__global__ void k_dis(const unsigned* __restrict__ dstptr, float* __restrict__ dis) {
  int n = blockIdx.x * 256 + threadIdx.x;
  int g = n >> 10, k = n & 1023;
  const unsigned* dp = dstptr + (size_t)g * (PP + 1) + k;
  float deg = (float)(dp[1] - dp[0]);
  dis[n] = 1.0f / sqrtf(deg + 1.0f);
}

// ---------------- GEMM1 via MFMA: hlin[row][0..31] = (x_row @ W1) * dis_row (fp16) --------
// 256 thr = 4 waves, block covers 256 rows; grid N/256 = 1024.
__global__ __launch_bounds__(256) void k_gemm1(const float* __restrict__ x,
                                               const float* __restrict__ dis,
                                               const float* __restrict__ W1,
                                               __half* __restrict__ hlin) {
  int t = threadIdx.x, b = blockIdx.x;
  int wv = t >> 6, lane = t & 63, quad = lane >> 4, l16 = lane & 15;
  half8 bfr[2][4];
#pragma unroll
  for (int nt = 0; nt < 2; ++nt)
#pragma unroll
    for (int kf = 0; kf < 4; ++kf) {
      half8 bb;
#pragma unroll
      for (int j = 0; j < 8; ++j)
        bb[j] = (_Float16)W1[(kf * 32 + quad * 8 + j) * HH + nt * 16 + l16];
      bfr[nt][kf] = bb;
    }
#pragma unroll
  for (int rt = 0; rt < 4; ++rt) {
    int row = b * 256 + wv * 64 + rt * 16 + l16;
    const float* xr = x + (size_t)row * FIN;
    half8 af[4];
#pragma unroll
    for (int kf = 0; kf < 4; ++kf) {
      float4 xa = *(const float4*)(xr + kf * 32 + quad * 8);
      float4 xb = *(const float4*)(xr + kf * 32 + quad * 8 + 4);
      half8 a;
      a[0] = (_Float16)xa.x; a[1] = (_Float16)xa.y; a[2] = (_Float16)xa.z; a[3] = (_Float16)xa.w;
      a[4] = (_Float16)xb.x; a[5] = (_Float16)xb.y; a[6] = (_Float16)xb.z; a[7] = (_Float16)xb.w;
      af[kf] = a;
    }
    int rb = b * 256 + wv * 64 + rt * 16 + quad * 4;
    float dv0 = dis[rb], dv1 = dis[rb + 1], dv2 = dis[rb + 2], dv3 = dis[rb + 3];
#pragma unroll
    for (int nt = 0; nt < 2; ++nt) {
      f32x4 acc = {0.f, 0.f, 0.f, 0.f};
      acc = __builtin_amdgcn_mfma_f32_16x16x32_f16(af[0], bfr[nt][0], acc, 0, 0, 0);
      acc = __builtin_amdgcn_mfma_f32_16x16x32_f16(af[1], bfr[nt][1], acc, 0, 0, 0);
      acc = __builtin_amdgcn_mfma_f32_16x16x32_f16(af[2], bfr[nt][2], acc, 0, 0, 0);
      acc = __builtin_amdgcn_mfma_f32_16x16x32_f16(af[3], bfr[nt][3], acc, 0, 0, 0);
      int col = nt * 16 + l16;
      hlin[(size_t)(rb + 0) * HH + col] = __float2half(acc[0] * dv0);
      hlin[(size_t)(rb + 1) * HH + col] = __float2half(acc[1] * dv1);
      hlin[(size_t)(rb + 2) * HH + col] = __float2half(acc[2] * dv2);
      hlin[(size_t)(rb + 3) * HH + col] = __float2half(acc[3] * dv3);
    }
  }
}

// ---------------- one GCN layer: 2 blocks/graph (512 dst each), full fp16 tile in LDS -----
// stage hlin tile (swizzled) -> gather+pk_add -> tanh -> h16 cols; optional in-thread
// 32x32 linear (W via s_load) -> hlin_next * d (fp16, global). 64KB LDS -> 2 blocks/CU.
__global__ __launch_bounds__(512, 1) void k_agg(const __half* __restrict__ hlin,
                                                const float* __restrict__ dis,
                                                const unsigned short* __restrict__ esrc16,
                                                const unsigned* __restrict__ dstptr,
                                                const float* __restrict__ bias,
                                                int coloff,
                                                const float* __restrict__ Wn,
                                                __half* __restrict__ h16,
                                                __half* __restrict__ hlin_next,
                                                float* __restrict__ keyArr) {
  __shared__ __half hsl[PP * 32];   // 64 KB swizzled fp16
  int t = threadIdx.x;
  int g = blockIdx.x >> 1, half = blockIdx.x & 1;
  // stage full graph tile: chunk p = t + 512*i (coalesced global read, swizzled LDS write)
  const uint4* src = (const uint4*)(hlin + (size_t)g * PP * HH);
#pragma unroll
  for (int i = 0; i < 8; ++i) {
    int p = t + i * 512;
    uint4 v = src[p];
    *(uint4*)&hsl[hslc(p >> 2, p & 3)] = v;
  }
  __syncthreads();

  int k = half * 512 + t;
  float dk = dis[(size_t)g * PP + k];
  const unsigned* dp = dstptr + (size_t)g * (PP + 1);
  const unsigned short* eg = esrc16 + (size_t)g * ECAP;
  unsigned e0 = dp[k], e1 = dp[k + 1];
  if (e1 > (unsigned)ECAP) e1 = ECAP;
  __half2 acc2[16];
  {
    uint4 u0 = *(const uint4*)&hsl[hslc(k, 0)];
    uint4 u1 = *(const uint4*)&hsl[hslc(k, 1)];
    uint4 u2 = *(const uint4*)&hsl[hslc(k, 2)];
    uint4 u3 = *(const uint4*)&hsl[hslc(k, 3)];
    acc2[0] = u2h2(u0.x); acc2[1] = u2h2(u0.y); acc2[2] = u2h2(u0.z); acc2[3] = u2h2(u0.w);
    acc2[4] = u2h2(u1.x); acc2[5] = u2h2(u1.y); acc2[6] = u2h2(u1.z); acc2[7] = u2h2(u1.w);
    acc2[8] = u2h2(u2.x); acc2[9] = u2h2(u2.y); acc2[10] = u2h2(u2.z); acc2[11] = u2h2(u2.w);
    acc2[12] = u2h2(u3.x); acc2[13] = u2h2(u3.y); acc2[14] = u2h2(u3.z); acc2[15] = u2h2(u3.w);
  }
  unsigned e = e0;
  for (; e + 1 < e1; e += 2) {
    int s0 = eg[e], s1 = eg[e + 1];
    uint4 a0 = *(const uint4*)&hsl[hslc(s0, 0)];
    uint4 a1 = *(const uint4*)&hsl[hslc(s0, 1)];
    uint4 a2 = *(const uint4*)&hsl[hslc(s0, 2)];
    uint4 a3 = *(const uint4*)&hsl[hslc(s0, 3)];
    uint4 b0 = *(const uint4*)&hsl[hslc(s1, 0)];
    uint4 b1 = *(const uint4*)&hsl[hslc(s1, 1)];
    uint4 b2 = *(const uint4*)&hsl[hslc(s1, 2)];
    uint4 b3 = *(const uint4*)&hsl[hslc(s1, 3)];
    acc2[0] = __hadd2(acc2[0], __hadd2(u2h2(a0.x), u2h2(b0.x)));
    acc2[1] = __hadd2(acc2[1], __hadd2(u2h2(a0.y), u2h2(b0.y)));
    acc2[2] = __hadd2(acc2[2], __hadd2(u2h2(a0.z), u2h2(b0.z)));
    acc2[3] = __hadd2(acc2[3], __hadd2(u2h2(a0.w), u2h2(b0.w)));
    acc2[4] = __hadd2(acc2[4], __hadd2(u2h2(a1.x), u2h2(b1.x)));
    acc2[5] = __hadd2(acc2[5], __hadd2(u2h2(a1.y), u2h2(b1.y)));
    acc2[6] = __hadd2(acc2[6], __hadd2(u2h2(a1.z), u2h2(b1.z)));
    acc2[7] = __hadd2(acc2[7], __hadd2(u2h2(a1.w), u2h2(b1.w)));
    acc2[8] = __hadd2(acc2[8], __hadd2(u2h2(a2.x), u2h2(b2.x)));
    acc2[9] = __hadd2(acc2[9], __hadd2(u2h2(a2.y), u2h2(b2.y)));
    acc2[10] = __hadd2(acc2[10], __hadd2(u2h2(a2.z), u2h2(b2.z)));
    acc2[11] = __hadd2(acc2[11], __hadd2(u2h2(a2.w), u2h2(b2.w)));
    acc2[12] = __hadd2(acc2[12], __hadd2(u2h2(a3.x), u2h2(b3.x)));
    acc2[13] = __hadd2(acc2[13], __hadd2(u2h2(a3.y), u2h2(b3.y)));
    acc2[14] = __hadd2(acc2[14], __hadd2(u2h2(a3.z), u2h2(b3.z)));
    acc2[15] = __hadd2(acc2[15], __hadd2(u2h2(a3.w), u2h2(b3.w)));
  }
  if (e < e1) {
    int s0 = eg[e];
    uint4 a0 = *(const uint4*)&hsl[hslc(s0, 0)];
    uint4 a1 = *(const uint4*)&hsl[hslc(s0, 1)];
    uint4 a2 = *(const uint4*)&hsl[hslc(s0, 2)];
    uint4 a3 = *(const uint4*)&hsl[hslc(s0, 3)];
    acc2[0] = __hadd2(acc2[0], u2h2(a0.x)); acc2[1] = __hadd2(acc2[1], u2h2(a0.y));
    acc2[2] = __hadd2(acc2[2], u2h2(a0.z)); acc2[3] = __hadd2(acc2[3], u2h2(a0.w));
    acc2[4] = __hadd2(acc2[4], u2h2(a1.x)); acc2[5] = __hadd2(acc2[5], u2h2(a1.y));
    acc2[6] = __hadd2(acc2[6], u2h2(a1.z)); acc2[7] = __hadd2(acc2[7], u2h2(a1.w));
    acc2[8] = __hadd2(acc2[8], u2h2(a2.x)); acc2[9] = __hadd2(acc2[9], u2h2(a2.y));
    acc2[10] = __hadd2(acc2[10], u2h2(a2.z)); acc2[11] = __hadd2(acc2[11], u2h2(a2.w));
    acc2[12] = __hadd2(acc2[12], u2h2(a3.x)); acc2[13] = __hadd2(acc2[13], u2h2(a3.y));
    acc2[14] = __hadd2(acc2[14], u2h2(a3.z)); acc2[15] = __hadd2(acc2[15], u2h2(a3.w));
  }
  // tanh + pack (bias via s_load)
  unsigned xnu[16];
  float lastv = 0.f;
#pragma unroll
  for (int i = 0; i < 16; ++i) {
    float2 f = __half22float2(acc2[i]);
    float a0 = tanh_fast(dk * f.x + bias[2 * i]);
    float a1 = tanh_fast(dk * f.y + bias[2 * i + 1]);
    xnu[i] = pk2(a0, a1);
    if (i == 15) lastv = a1;
  }
  __half* hr = h16 + (size_t)((size_t)g * PP + k) * IL + coloff;
  {
    uint4 h0, h1, h2, h3;
    h0.x = xnu[0]; h0.y = xnu[1]; h0.z = xnu[2]; h0.w = xnu[3];
    h1.x = xnu[4]; h1.y = xnu[5]; h1.z = xnu[6]; h1.w = xnu[7];
    h2.x = xnu[8]; h2.y = xnu[9]; h2.z = xnu[10]; h2.w = xnu[11];
    h3.x = xnu[12]; h3.y = xnu[13]; h3.z = xnu[14]; h3.w = xnu[15];
    ((uint4*)hr)[0] = h0; ((uint4*)hr)[1] = h1;
    ((uint4*)hr)[2] = h2; ((uint4*)hr)[3] = h3;
  }
  if (keyArr) keyArr[(size_t)g * PP + k] = lastv;
  if (Wn) {
    float4 o4[8];
#pragma unroll
    for (int j = 0; j < 8; ++j) { o4[j].x = 0.f; o4[j].y = 0.f; o4[j].z = 0.f; o4[j].w = 0.f; }
#pragma unroll
    for (int c2 = 0; c2 < 16; ++c2) {
      float2 xc = __half22float2(u2h2(xnu[c2]));
      const float4* wr0 = (const float4*)(Wn + (2 * c2) * 32);       // uniform -> s_load
      const float4* wr1 = (const float4*)(Wn + (2 * c2 + 1) * 32);
#pragma unroll
      for (int j4 = 0; j4 < 8; ++j4) {
        float4 w0 = wr0[j4], w1 = wr1[j4];
        o4[j4].x += xc.x * w0.x + xc.y * w1.x;
        o4[j4].y += xc.x * w0.y + xc.y * w1.y;
        o4[j4].z += xc.x * w0.z + xc.y * w1.z;
        o4[j4].w += xc.x * w0.w + xc.y * w1.w;
      }
    }
    __half* op = hlin_next + (size_t)((size_t)g * PP + k) * HH;
    uint4 u0, u1, u2, u3;
    u0.x = pk2(o4[0].x * dk, o4[0].y * dk); u0.y = pk2(o4[0].z * dk, o4[0].w * dk);
    u0.z = pk2(o4[1].x * dk, o4[1].y * dk); u0.w = pk2(o4[1].z * dk, o4[1].w * dk);
    u1.x = pk2(o4[2].x * dk, o4[2].y * dk); u1.y = pk2(o4[2].z * dk, o4[2].w * dk);
    u1.z = pk2(o4[3].x * dk, o4[3].y * dk); u1.w = pk2(o4[3].z * dk, o4[3].w * dk);
    u2.x = pk2(o4[4].x * dk, o4[4].y * dk); u2.y = pk2(o4[4].z * dk, o4[4].w * dk);
    u2.z = pk2(o4[5].x * dk, o4[5].y * dk); u2.w = pk2(o4[5].z * dk, o4[5].w * dk);
    u3.x = pk2(o4[6].x * dk, o4[6].y * dk); u3.y = pk2(o4[6].z * dk, o4[6].w * dk);
    u3.z = pk2(o4[7].x * dk, o4[7].y * dk); u3.w = pk2(o4[7].z * dk, o4[7].w * dk);
    ((uint4*)op)[0] = u0; ((uint4*)op)[1] = u1;
    ((uint4*)op)[2] = u2; ((uint4*)op)[3] = u3;
  }
}

// ---------------- per-graph stable descending sort by fp32 key (bitonic, 512 thr) ---------
__global__ __launch_bounds__(512) void k_sort(const float* __restrict__ keyArr,
                                              unsigned short* __restrict__ rank16) {
  __shared__ float key[PP];
  __shared__ unsigned sidx[PP];
  int t = threadIdx.x, g = blockIdx.x;
  for (int i = t; i < PP; i += 512) {
    key[i] = keyArr[(size_t)g * PP + i];
    sidx[i] = i;
  }
  __syncthreads();
  for (int sz = 2; sz <= PP; sz <<= 1) {
    for (int st = sz >> 1; st > 0; st >>= 1) {
      int i = 2 * t - (t & (st - 1));
      int j = i + st;
      float ki = key[i], kj = key[j];
      unsigned ii = sidx[i], ij = sidx[j];
      bool less_ji = (kj > ki) || (kj == ki && ij < ii);
      bool asc = ((i & sz) == 0);
      if (less_ji == asc) { key[i] = kj; key[j] = ki; sidx[i] = ij; sidx[j] = ii; }
      __syncthreads();
    }
  }
  for (int i = t; i < PP; i += 512) rank16[g * PP + sidx[i]] = (unsigned short)i;
}

// ---------------- position encoding ----------------
__global__ void k_pe(float* __restrict__ pe) {
  int id = blockIdx.x * 256 + threadIdx.x;
  if (id >= PP * 48) return;
  int pos = id / 48, i = id % 48;
  float denom = powf(10000.0f, (2.0f * i) / 96.0f);
  float ang = (float)pos / denom;
  pe[pos * IL + 2 * i] = sinf(ang);
  pe[pos * IL + 2 * i + 1] = cosf(ang);
}

// ---------------- WPE[c][pos][j] = sum_i capsW[c][j][i] * pe[pos][i], fp16 ----------------
__global__ void k_wpe(const float* __restrict__ pe, const float* __restrict__ capsW,
                      __half* __restrict__ wpe) {
  int id = blockIdx.x * 256 + threadIdx.x;
  if (id >= NC * PP * OL) return;
  int j = id & 15;
  int pos = (id >> 4) & 1023;
  int c = id >> 14;
  const float* wr = capsW + (size_t)(c * OL + j) * IL;
  const float* pr = pe + (size_t)pos * IL;
  float a = 0;
#pragma unroll 8
  for (int i = 0; i < IL; ++i) a += wr[i] * pr[i];
  wpe[(((size_t)c << 10) + pos) * 16 + j] = __float2half(a);
}

// ---------------- priors GEMM via MFMA f16: Pc[g][c][k][16] = h16[k] @ capsW[c*16+j] -------
__global__ __launch_bounds__(256) void k_pgemm(const __half* __restrict__ h16,
                                               const float* __restrict__ capsW,
                                               __half* __restrict__ Pc) {
  int t = threadIdx.x, b = blockIdx.x;
  int g = b >> 2;
  int wv = t >> 6, lane = t & 63;
  int quad = lane >> 4, l16 = lane & 15;
  half8 afr[4][3];
#pragma unroll
  for (int rt = 0; rt < 4; ++rt) {
    int row = b * 256 + wv * 64 + rt * 16 + l16;
    const __half* hr = h16 + (size_t)row * IL + quad * 8;
#pragma unroll
    for (int kb = 0; kb < 3; ++kb) {
      uint4 u = *(const uint4*)(hr + kb * 32);
      afr[rt][kb] = __builtin_bit_cast(half8, u);
    }
  }
  int krow_base = (b & 3) * 256 + wv * 64;
  for (int ct = 0; ct < NC; ++ct) {
    half8 bfr[3];
    const float* wr = capsW + (size_t)(ct * 16 + l16) * IL + quad * 8;
#pragma unroll
    for (int kb = 0; kb < 3; ++kb) {
      float4 xx = *(const float4*)(wr + kb * 32);
      float4 yy = *(const float4*)(wr + kb * 32 + 4);
      half8 bb;
      bb[0] = (_Float16)xx.x; bb[1] = (_Float16)xx.y; bb[2] = (_Float16)xx.z; bb[3] = (_Float16)xx.w;
      bb[4] = (_Float16)yy.x; bb[5] = (_Float16)yy.y; bb[6] = (_Float16)yy.z; bb[7] = (_Float16)yy.w;
      bfr[kb] = bb;
    }
#pragma unroll
    for (int rt = 0; rt < 4; ++rt) {
      f32x4 acc = {0.f, 0.f, 0.f, 0.f};
      acc = __builtin_amdgcn_mfma_f32_16x16x32_f16(afr[rt][0], bfr[0], acc, 0, 0, 0);
      acc = __builtin_amdgcn_mfma_f32_16x16x32_f16(afr[rt][1], bfr[1], acc, 0, 0, 0);
      acc = __builtin_amdgcn_mfma_f32_16x16x32_f16(afr[rt][2], bfr[2], acc, 0, 0, 0);
      int krow = krow_base + rt * 16;
      __half* po = Pc + ((((size_t)g * NC + ct) << 10) + krow) * 16 + l16;
#pragma unroll
      for (int r = 0; r < 4; ++r)
        po[(quad * 4 + r) * 16] = __float2half(acc[r]);
    }
  }
}

// ---------------- routing: one block per (graph, capsule), P rows in registers ----------------
__global__ __launch_bounds__(256) void k_route2(const __half* __restrict__ Pc,
                                                const __half* __restrict__ wpe,
                                                const unsigned short* __restrict__ rank16,
                                                float* __restrict__ out) {
  __shared__ float v_l[16];
  __shared__ float wred[4][17];
  int t = threadIdx.x;
  int gc = blockIdx.x;
  int g = gc / NC, c = gc - g * NC;
  int lane = t & 63, wv = t >> 6;
  const __half* pg = Pc + ((size_t)gc << 10) * 16;
  const unsigned short* rk = rank16 + (size_t)g * PP;
  const __half* wc = wpe + ((size_t)c << 10) * 16;
  float pr[4][16];
  float vsum[16];
#pragma unroll
  for (int i = 0; i < 16; ++i) vsum[i] = 0.f;
#pragma unroll
  for (int r = 0; r < 4; ++r) {
    int k = t + r * 256;
    uint4 a0 = *(const uint4*)(pg + (size_t)k * 16);
    uint4 a1 = *(const uint4*)(pg + (size_t)k * 16 + 8);
    int rkk = rk[k];
    uint4 b0 = *(const uint4*)(wc + (size_t)rkk * 16);
    uint4 b1 = *(const uint4*)(wc + (size_t)rkk * 16 + 8);
    const __half2* pa0 = (const __half2*)&a0; const __half2* pa1 = (const __half2*)&a1;
    const __half2* pb0 = (const __half2*)&b0; const __half2* pb1 = (const __half2*)&b1;
#pragma unroll
    for (int j = 0; j < 4; ++j) {
      float2 fa = __half22float2(pa0[j]); float2 fb = __half22float2(pb0[j]);
      pr[r][2 * j] = fa.x + fb.x; pr[r][2 * j + 1] = fa.y + fb.y;
      float2 fa1 = __half22float2(pa1[j]); float2 fb1 = __half22float2(pb1[j]);
      pr[r][8 + 2 * j] = fa1.x + fb1.x; pr[r][8 + 2 * j + 1] = fa1.y + fb1.y;
    }
#pragma unroll
    for (int i = 0; i < 16; ++i) vsum[i] += pr[r][i];
  }
#pragma unroll
  for (int d = 1; d < 64; d <<= 1)
#pragma unroll
    for (int i = 0; i < 16; ++i) vsum[i] += __shfl_xor(vsum[i], d, 64);
  if (lane == 0) {
#pragma unroll
    for (int i = 0; i < 16; ++i) wred[wv][i] = vsum[i];
  }
  __syncthreads();
  if (t < 16) v_l[t] = wred[0][t] + wred[1][t] + wred[2][t] + wred[3][t];
  __syncthreads();
  for (int it = 0; it < NITER; ++it) {
    float vn[16]; float n2 = 0;
#pragma unroll
    for (int i = 0; i < 16; ++i) { float x = v_l[i]; vn[i] = x; n2 += x * x; }
    float inv = 1.0f / (sqrtf(n2) + 1e-12f);
#pragma unroll
    for (int i = 0; i < 16; ++i) vn[i] *= inv;
    float lg[4];
#pragma unroll
    for (int r = 0; r < 4; ++r) {
      float a = 0;
#pragma unroll
      for (int i = 0; i < 16; ++i) a += pr[r][i] * vn[i];
      lg[r] = a;
    }
    float mx = fmaxf(fmaxf(lg[0], lg[1]), fmaxf(lg[2], lg[3]));
#pragma unroll
    for (int d = 1; d < 64; d <<= 1) mx = fmaxf(mx, __shfl_xor(mx, d, 64));
    __syncthreads();   // wred safe to rewrite
    if (lane == 0) wred[wv][16] = mx;
    __syncthreads();
    float gmax = fmaxf(fmaxf(wred[0][16], wred[1][16]), fmaxf(wred[2][16], wred[3][16]));
    float es = 0; float eacc[16];
#pragma unroll
    for (int i = 0; i < 16; ++i) eacc[i] = 0.f;
#pragma unroll
    for (int r = 0; r < 4; ++r) {
      float e = __expf(lg[r] - gmax);
      es += e;
#pragma unroll
      for (int i = 0; i < 16; ++i) eacc[i] += e * pr[r][i];
    }
#pragma unroll
    for (int d = 1; d < 64; d <<= 1) {
      es += __shfl_xor(es, d, 64);
#pragma unroll
      for (int i = 0; i < 16; ++i) eacc[i] += __shfl_xor(eacc[i], d, 64);
    }
    __syncthreads();   // gmax consumed by all waves
    if (lane == 0) {
#pragma unroll
      for (int i = 0; i < 16; ++i) wred[wv][i] = eacc[i];
      wred[wv][16] = es;
    }
    __syncthreads();
    if (t < 16) {
      float s = wred[0][t] + wred[1][t] + wred[2][t] + wred[3][t];
      float S = wred[0][16] + wred[1][16] + wred[2][16] + wred[3][16];
      v_l[t] = s / S;
    }
    __syncthreads();
  }
  if (t == 0) {
    float n2 = 0;
#pragma unroll
    for (int i = 0; i < 16; ++i) { float x = v_l[i]; n2 += x * x; }
    out[gc] = (n2 / (1.0f + n2)) * sqrtf(n2) / sqrtf(n2 + 1e-12f);
  }
}

extern "C" void kernel_launch(void* const* d_in, const int* in_sizes, int n_in,
                              void* d_out, int out_size, void* d_ws, size_t ws_size,
                              hipStream_t stream) {
  const float* x     = (const float*)d_in[0];
  const int*   ei    = (const int*)d_in[1];
  const float* W1    = (const float*)d_in[3];
  const float* b1    = (const float*)d_in[4];
  const float* W2    = (const float*)d_in[5];
  const float* b2    = (const float*)d_in[6];
  const float* W3    = (const float*)d_in[7];
  const float* b3    = (const float*)d_in[8];
  const float* capsW = (const float*)d_in[9];
  float* out = (float*)d_out;

  char* wp = (char*)d_ws;
  auto alloc = [&](size_t bytes) { char* p = wp; wp += (bytes + 255) & ~(size_t)255; return p; };
  float*    dis    = (float*)alloc((size_t)N_NODES * 4);
  __half*   h16    = (__half*)alloc((size_t)N_NODES * IL * 2);           // 50 MB
  float*    key    = (float*)alloc((size_t)N_NODES * 4);                 // 1 MB
  // --- union region (later fully overlaid by Pc, 80 MiB):
  // [epack 16M / hlinA 16M] [hlinB 16M] [esrc16 9M] [histT 1M] [cbaseT 1M]
  // epack dead after k_dstsort (before k_gemm1 writes hlinA);
  // hlinA/hlinB/esrc16/histT/cbaseT dead before k_pgemm writes Pc.
  char*     ureg   = wp;
  unsigned* epack  = (unsigned*)alloc((size_t)NE * 4);                   // 16 MB
  __half*   hlinA  = (__half*)epack;                                     // 16 MB alias
  __half*   hlinB  = (__half*)alloc((size_t)N_NODES * HH * 2);           // 16 MB
  unsigned short* esrc16 = (unsigned short*)alloc((size_t)NG * ECAP * 2);// 9 MB
  unsigned* histT  = (unsigned*)alloc((size_t)NCHUNK * NG * 4);          // 1 MB
  unsigned* cbaseT = (unsigned*)alloc((size_t)NCHUNK * NG * 4);          // 1 MB
  const size_t PC_BYTES = (size_t)NG * NC * PP * 16 * 2;                 // 80 MiB
  if ((size_t)(wp - ureg) < PC_BYTES) wp = ureg + ((PC_BYTES + 255) & ~(size_t)255);
  __half*   Pc     = (__half*)ureg;                                      // overlays union
  unsigned* gtot   = (unsigned*)alloc((size_t)NG * 4);
  unsigned* gbase  = (unsigned*)alloc((size_t)(NG + 1) * 4);
  unsigned* dstptr = (unsigned*)alloc((size_t)NG * (PP + 1) * 4);
  unsigned short* rank16 = (unsigned short*)alloc((size_t)NG * PP * 2);
  float*    pe     = (float*)alloc((size_t)PP * IL * 4);
  __half*   wpe    = (__half*)alloc((size_t)NC * PP * OL * 2);

  k_hist<<<NCHUNK, 256, 0, stream>>>(ei, histT);
  k_scanA<<<NG, 256, 0, stream>>>(histT, cbaseT, gtot);
  k_scanB<<<1, 256, 0, stream>>>(gtot, gbase);
  k_scatter<<<NCHUNK, 256, 0, stream>>>(ei, cbaseT, gbase, epack);
  k_dstsort<<<NG, 256, 0, stream>>>(epack, gbase, esrc16, dstptr);
  k_dis<<<N_NODES / 256, 256, 0, stream>>>(dstptr, dis);
  k_pe<<<(PP * 48) / 256, 256, 0, stream>>>(pe);
  k_wpe<<<(NC * PP * OL) / 256, 256, 0, stream>>>(pe, capsW, wpe);

  k_gemm1<<<N_NODES / 256, 256, 0, stream>>>(x, dis, W1, hlinA);
  k_agg<<<NG * 2, 512, 0, stream>>>(hlinA, dis, esrc16, dstptr, b1, 0,  W2, h16, hlinB, nullptr);
  k_agg<<<NG * 2, 512, 0, stream>>>(hlinB, dis, esrc16, dstptr, b2, 32, W3, h16, hlinA, nullptr);
  k_agg<<<NG * 2, 512, 0, stream>>>(hlinA, dis, esrc16, dstptr, b3, 64, nullptr, h16, nullptr, key);

  k_sort<<<NG, 512, 0, stream>>>(key, rank16);
  k_pgemm<<<N_NODES / 256, 256, 0, stream>>>(h16, capsW, Pc);   // Pc overlays dead buffers
  k_route2<<<NG * NC, 256, 0, stream>>>(Pc, wpe, rank16, out);
}